// Round 5
// baseline (1379.336 us; speedup 1.0000x reference)
//
#include <hip/hip_runtime.h>

// Vector quantization: z [32768,256] f32, codebook [8192,256] f32
// outputs: z_q [32768,256] f32, indices [32768] (as float)
//
// Single-pass bf16 MFMA screening (guaranteed margin bound) -> candidates;
// exact pass re-evaluates with the bitwise round-2 f32 chain (passed, absmax 0).

#define NROWS 32768
#define DIM   256
#define KCB   8192
#define CANDCAP 64
#define MARGIN  1.2e-3f

// float offsets into d_out scratch (z_q region; gather overwrites last)
#define OFF_CAND  0          // u16 [32768][64]  (4 MB)
#define OFF_CNT   1048576    // u32 [32768]
#define OFF_ZSQ   1081344    // f32 [32768]
#define OFF_CSQ   1114112    // f32 [8192]
#define OFF_ZHSW  1122304    // bf16 A fragment-ordered image (16 MB)
#define OFF_CBSW  5316608    // bf16 B pre-swizzled tile image (4 MB)
#define OFF_IDX   8388608    // final indices (float) - real output tail

using bf16x8 = __attribute__((ext_vector_type(8))) short;
using f32x4  = __attribute__((ext_vector_type(4))) float;

__device__ __forceinline__ unsigned short bf16rne(float f) {
    unsigned u = __float_as_uint(f);
    unsigned r = u + 0x7FFFu + ((u >> 16) & 1u);
    return (unsigned short)(r >> 16);
}

__device__ __forceinline__ void gld_lds16(const void* g, void* l) {
    __builtin_amdgcn_global_load_lds(
        (const __attribute__((address_space(1))) void*)g,
        (__attribute__((address_space(3))) void*)l, 16, 0, 0);
}

// numpy pairwise sum of squares, n=256, bitwise-faithful (verified rounds 2-4).
__device__ float np_sumsq_256(const float* __restrict__ p) {
#pragma clang fp contract(off)
    float blk[2];
    #pragma unroll
    for (int b = 0; b < 2; ++b) {
        const float* q = p + b * 128;
        float r[8];
        #pragma unroll
        for (int j = 0; j < 8; ++j) r[j] = __fmul_rn(q[j], q[j]);
        for (int i = 8; i < 128; i += 8) {
            #pragma unroll
            for (int j = 0; j < 8; ++j)
                r[j] = __fadd_rn(r[j], __fmul_rn(q[i + j], q[i + j]));
        }
        blk[b] = __fadd_rn(
            __fadd_rn(__fadd_rn(r[0], r[1]), __fadd_rn(r[2], r[3])),
            __fadd_rn(__fadd_rn(r[4], r[5]), __fadd_rn(r[6], r[7])));
    }
    return __fadd_rn(blk[0], blk[1]);
}

__global__ void vq_sumsq_kernel(const float* __restrict__ a,
                                float* __restrict__ out, int nrows) {
    int r = blockIdx.x * blockDim.x + threadIdx.x;
    if (r < nrows) out[r] = np_sumsq_256(a + (size_t)r * DIM);
}

__global__ void vq_init_kernel(unsigned* __restrict__ cnt) {
    int i = blockIdx.x * 256 + threadIdx.x;
    if (i < NROWS) cnt[i] = 0;
}

// A image: [blk 256][wr 2][m 4][kk 8][lane 64] x 16B. Lane's 8 bf16 =
// z[blk*128+wr*64+m*16+(lane&15)][kk*32+(lane>>4)*8 .. +8)
__global__ void vq_cvtA_kernel(const float* __restrict__ z, uint4* __restrict__ zhsw) {
    int t = blockIdx.x * 256 + threadIdx.x;       // 0..1048575
    int lane = t & 63, kk = (t >> 6) & 7, m = (t >> 9) & 3, wr = (t >> 11) & 1, b = t >> 12;
    int row = b * 128 + wr * 64 + m * 16 + (lane & 15);
    int k0  = kk * 32 + (lane >> 4) * 8;
    const float* src = &z[(size_t)row * DIM + k0];
    float4 v0 = *reinterpret_cast<const float4*>(src);
    float4 v1 = *reinterpret_cast<const float4*>(src + 4);
    uint4 o;
    o.x = (unsigned)bf16rne(v0.x) | ((unsigned)bf16rne(v0.y) << 16);
    o.y = (unsigned)bf16rne(v0.z) | ((unsigned)bf16rne(v0.w) << 16);
    o.z = (unsigned)bf16rne(v1.x) | ((unsigned)bf16rne(v1.y) << 16);
    o.w = (unsigned)bf16rne(v1.z) | ((unsigned)bf16rne(v1.w) << 16);
    zhsw[t] = o;
}

// B image: [ct 64][kk 8][cc 128][64B row]; byte-in-row = (lhi*16)^((cc&3)<<4)
// holds cb[ct*128+cc][kk*32+lhi*8 .. +8) as bf16. Linear global_load_lds then
// swizzled ds_read_b128 is bank-uniform.
__global__ void vq_cvtB_kernel(const float* __restrict__ cb, uint4* __restrict__ cbsw) {
    int t = blockIdx.x * 256 + threadIdx.x;       // 0..262143
    int s4 = t & 3, cc = (t >> 2) & 127, kk = (t >> 9) & 7, ct = t >> 12;
    int lhi = s4 ^ (cc & 3);
    int k0 = kk * 32 + lhi * 8;
    const float* src = &cb[(size_t)(ct * 128 + cc) * DIM + k0];
    float4 v0 = *reinterpret_cast<const float4*>(src);
    float4 v1 = *reinterpret_cast<const float4*>(src + 4);
    uint4 o;
    o.x = (unsigned)bf16rne(v0.x) | ((unsigned)bf16rne(v0.y) << 16);
    o.y = (unsigned)bf16rne(v0.z) | ((unsigned)bf16rne(v0.w) << 16);
    o.z = (unsigned)bf16rne(v1.x) | ((unsigned)bf16rne(v1.y) << 16);
    o.w = (unsigned)bf16rne(v1.z) | ((unsigned)bf16rne(v1.w) << 16);
    cbsw[t] = o;
}

// ---------------- MFMA screen ----------------
// Grid 256 (1 block/CU). Block: 128 rows x 8192 codes, 64 tiles of 128 codes.
// 8 waves = 2(row) x 4(code); wave tile 64x32: acc[m 4][n 2] f32x4.
// A (z) lives in registers for the whole loop; B double-buffered in LDS via
// global_load_lds from the pre-swizzled image.
__global__ __launch_bounds__(512, 2) void vq_screen_kernel(
    const uint4* __restrict__ zhsw, const char* __restrict__ cbsw,
    const float* __restrict__ zsq, const float* __restrict__ csq,
    unsigned* __restrict__ cnt, unsigned short* __restrict__ cand) {
    __shared__ __align__(16) unsigned char Bbuf[2][65536];
    __shared__ float runmin[128];
    const int tid = threadIdx.x, lane = tid & 63, wid = tid >> 6;
    const int wr = wid >> 2, wc = wid & 3;
    const int l15 = lane & 15, lhi = lane >> 4;
    const int b = blockIdx.x, row0 = b * 128;

    // A fragments -> 128 VGPRs (coalesced 1KB wave reads)
    bf16x8 ah[4][8];
    {
        const uint4* abase = zhsw + (size_t)b * 4096 + wr * 2048 + lane;
        #pragma unroll
        for (int m = 0; m < 4; ++m)
            #pragma unroll
            for (int kk = 0; kk < 8; ++kk)
                ah[m][kk] = __builtin_bit_cast(bf16x8, abase[m * 512 + kk * 64]);
    }

    float Zr[4][4];
    #pragma unroll
    for (int m = 0; m < 4; ++m) {
        float4 zq = *reinterpret_cast<const float4*>(&zsq[row0 + wr * 64 + m * 16 + lhi * 4]);
        Zr[m][0] = zq.x; Zr[m][1] = zq.y; Zr[m][2] = zq.z; Zr[m][3] = zq.w;
    }

    f32x4 acc[4][2];
    auto ZERO = [&]() {
        #pragma unroll
        for (int m = 0; m < 4; ++m)
            #pragma unroll
            for (int n = 0; n < 2; ++n) acc[m][n] = (f32x4){0.f, 0.f, 0.f, 0.f};
    };
    ZERO();

    auto STAGE = [&](int buf, int ct2) {   // wave wid copies its 8KB chunk
        const char* g = cbsw + (size_t)ct2 * 65536 + wid * 8192 + lane * 16;
        unsigned char* l = &Bbuf[buf][wid * 8192];
        #pragma unroll
        for (int i = 0; i < 8; ++i)
            gld_lds16(g + i * 1024, l + i * 1024);
    };

    auto MFMA = [&](int buf) {
        const int cc0 = wc * 32 + l15, cc1 = cc0 + 16;
        const int sw0 = (lhi * 16) ^ ((cc0 & 3) << 4);
        const int sw1 = (lhi * 16) ^ ((cc1 & 3) << 4);
        #pragma unroll
        for (int kk = 0; kk < 8; ++kk) {
            bf16x8 bh0 = *reinterpret_cast<const bf16x8*>(&Bbuf[buf][kk * 8192 + cc0 * 64 + sw0]);
            bf16x8 bh1 = *reinterpret_cast<const bf16x8*>(&Bbuf[buf][kk * 8192 + cc1 * 64 + sw1]);
            #pragma unroll
            for (int m = 0; m < 4; ++m) {
                acc[m][0] = __builtin_amdgcn_mfma_f32_16x16x32_bf16(ah[m][kk], bh0, acc[m][0], 0, 0, 0);
                acc[m][1] = __builtin_amdgcn_mfma_f32_16x16x32_bf16(ah[m][kk], bh1, acc[m][1], 0, 0, 0);
            }
        }
    };

    auto EPI = [&](int ct, bool collect) {
        float cs0 = csq[ct * 128 + wc * 32 + l15];
        float cs1 = csq[ct * 128 + wc * 32 + 16 + l15];
        #pragma unroll
        for (int m = 0; m < 4; ++m) {
            float4 rmv = *reinterpret_cast<const float4*>(&runmin[wr * 64 + m * 16 + lhi * 4]);
            #pragma unroll
            for (int r = 0; r < 4; ++r) {
                const float rm = (r == 0) ? rmv.x : (r == 1) ? rmv.y : (r == 2) ? rmv.z : rmv.w;
                const int lr = wr * 64 + m * 16 + lhi * 4 + r;
                #pragma unroll
                for (int n = 0; n < 2; ++n) {
                    float s = __fadd_rn(__fsub_rn(Zr[m][r], __fmul_rn(2.0f, acc[m][n][r])),
                                        n ? cs1 : cs0);
                    if (s < rm)
                        atomicMin((unsigned*)&runmin[lr], __float_as_uint(s));
                    if (collect && s < rm + MARGIN) {
                        int grow = row0 + lr;
                        unsigned slot = atomicAdd(&cnt[grow], 1u);
                        if (slot < CANDCAP)
                            cand[(size_t)grow * CANDCAP + slot] =
                                (unsigned short)(ct * 128 + wc * 32 + n * 16 + l15);
                    }
                }
            }
        }
    };

    STAGE(0, 0);
    if (tid < 128) runmin[tid] = 3.4e38f;
    __syncthreads();                 // stage(0) drained + runmin visible

    // ct = 0: establish runmin first, collect after (avoids cap flood)
    STAGE(1, 1);
    MFMA(0);
    EPI(0, false);
    __syncthreads();                 // ct0 runmin complete + stage(1) drained
    EPI(0, true);
    ZERO();
    __syncthreads();

    for (int ct = 1; ct < 64; ++ct) {
        const int buf = ct & 1;
        if (ct < 63) STAGE(buf ^ 1, ct + 1);
        MFMA(buf);
        EPI(ct, true);
        ZERO();
        __syncthreads();             // drains stage(ct+1), syncs runmin
    }
}

// ---------------- exact resolve (verbatim from passing round 4) ----------------
__global__ __launch_bounds__(256) void vq_exact_kernel(
    const float* __restrict__ z, const float* __restrict__ cb,
    const float* __restrict__ zsq, const float* __restrict__ csq,
    const unsigned* __restrict__ cnt, const unsigned short* __restrict__ cand,
    float* __restrict__ idxF) {
    __shared__ float zrow[4][DIM];
    const int wid = threadIdx.x >> 6, lane = threadIdx.x & 63;
    const int row = blockIdx.x * 4 + wid;

    float4 zv4 = *reinterpret_cast<const float4*>(&z[(size_t)row * DIM + lane * 4]);
    *reinterpret_cast<float4*>(&zrow[wid][lane * 4]) = zv4;
    __syncthreads();

    const float Zr = zsq[row];
    const float4* cb4 = reinterpret_cast<const float4*>(cb);
    float best = 3.4e38f;
    int   bi   = 0x7FFFFFFF;
    const unsigned c = cnt[row];

    if (c > 0 && c <= CANDCAP) {
        if (lane < (int)c) {
            int k = cand[(size_t)row * CANDCAP + lane];
            float a = 0.0f;
            #pragma unroll 8
            for (int q = 0; q < 64; ++q) {
                float4 cv = cb4[(size_t)k * 64 + q];
                float4 zv = *reinterpret_cast<const float4*>(&zrow[wid][q * 4]);
                a = fmaf(zv.x, cv.x, a); a = fmaf(zv.y, cv.y, a);
                a = fmaf(zv.z, cv.z, a); a = fmaf(zv.w, cv.w, a);
            }
            best = __fadd_rn(__fsub_rn(Zr, __fmul_rn(2.0f, a)), csq[k]);
            bi = k;
        }
    } else {
        for (int k = lane; k < KCB; k += 64) {
            float a = 0.0f;
            #pragma unroll 8
            for (int q = 0; q < 64; ++q) {
                float4 cv = cb4[(size_t)k * 64 + q];
                float4 zv = *reinterpret_cast<const float4*>(&zrow[wid][q * 4]);
                a = fmaf(zv.x, cv.x, a); a = fmaf(zv.y, cv.y, a);
                a = fmaf(zv.z, cv.z, a); a = fmaf(zv.w, cv.w, a);
            }
            float sv = __fadd_rn(__fsub_rn(Zr, __fmul_rn(2.0f, a)), csq[k]);
            if (sv < best || (sv == best && k < bi)) { best = sv; bi = k; }
        }
    }
    #pragma unroll
    for (int mk = 32; mk >= 1; mk >>= 1) {
        float ov = __shfl_xor(best, mk);
        int   oi = __shfl_xor(bi, mk);
        if (ov < best || (ov == best && oi < bi)) { best = ov; bi = oi; }
    }
    if (lane == 0) idxF[row] = (float)bi;
}

__global__ void vq_gather_kernel(const float* __restrict__ cb,
                                 const float* __restrict__ idxF,
                                 float4* __restrict__ out4) {
    int g = blockIdx.x * blockDim.x + threadIdx.x;
    const float4* cb4 = reinterpret_cast<const float4*>(cb);
    for (int i = g; i < NROWS * 64; i += gridDim.x * blockDim.x) {
        int row = i >> 6, q = i & 63;
        int idx = (int)idxF[row];
        out4[i] = cb4[(size_t)idx * 64 + q];
    }
}

extern "C" void kernel_launch(void* const* d_in, const int* in_sizes, int n_in,
                              void* d_out, int out_size, void* d_ws, size_t ws_size,
                              hipStream_t stream) {
    const float* z  = (const float*)d_in[0];
    const float* cb = (const float*)d_in[1];
    float* out = (float*)d_out;

    unsigned short* candp = (unsigned short*)(out + OFF_CAND);
    unsigned*       cntp  = (unsigned*)(out + OFF_CNT);
    float*          zsq   = out + OFF_ZSQ;
    float*          csq   = out + OFF_CSQ;
    uint4*          zhsw  = (uint4*)(out + OFF_ZHSW);
    uint4*          cbsw  = (uint4*)(out + OFF_CBSW);
    float*          idxF  = out + OFF_IDX;

    vq_sumsq_kernel<<<KCB / 256, 256, 0, stream>>>(cb, csq, KCB);
    vq_sumsq_kernel<<<NROWS / 256, 256, 0, stream>>>(z, zsq, NROWS);
    vq_init_kernel<<<NROWS / 256, 256, 0, stream>>>(cntp);
    vq_cvtA_kernel<<<4096, 256, 0, stream>>>(z, zhsw);
    vq_cvtB_kernel<<<1024, 256, 0, stream>>>(cb, cbsw);
    vq_screen_kernel<<<256, 512, 0, stream>>>(zhsw, (const char*)cbsw, zsq, csq, cntp, candp);
    vq_exact_kernel<<<NROWS / 4, 256, 0, stream>>>(z, cb, zsq, csq, cntp, candp, idxF);
    vq_gather_kernel<<<2048, 256, 0, stream>>>(cb, idxF, (float4*)out);
}

// Round 6
// 438.558 us; speedup vs baseline: 3.1452x; 3.1452x over previous
//
#include <hip/hip_runtime.h>

// Vector quantization: z [32768,256] f32, codebook [8192,256] f32
// outputs: z_q [32768,256] f32, indices [32768] (as float)
//
// Single-pass bf16 MFMA screening (margin-bounded candidates) -> exact pass
// re-evaluates candidates with the bitwise round-2 f32 chain (absmax 0 in
// rounds 2-5). Overflow rows (never expected) go to a cleanup kernel instead
// of an in-kernel full scan (round-5 lesson: scattered full scans are a
// transaction-bound 1 ms tail).

#define NROWS 32768
#define DIM   256
#define KCB   8192
#define CANDCAP 128
#define MARGIN  4.5e-4f

// float-slot offsets into d_out scratch (z_q region; gather overwrites last)
#define OFF_CAND  0          // u16 [32768][128] (8 MB)
#define OFF_CNT   2097152    // u32 [32768]
#define OFF_ZSQ   2129920    // f32 [32768]
#define OFF_CSQ   2162688    // f32 [8192]
#define OFF_OVL   2170880    // u32 [32768] overflow row list
#define OFF_OVC   2203648    // u32 overflow count (+pad)
#define OFF_ZHSW  2203664    // bf16 A fragment-ordered image (16 MB, 16B-aligned)
#define OFF_CBSW  6397968    // bf16 B pre-swizzled tile image (4 MB)
#define OFF_IDX   8388608    // final indices (float) - real output tail

using bf16x8 = __attribute__((ext_vector_type(8))) short;
using f32x4  = __attribute__((ext_vector_type(4))) float;

__device__ __forceinline__ unsigned short bf16rne(float f) {
    unsigned u = __float_as_uint(f);
    unsigned r = u + 0x7FFFu + ((u >> 16) & 1u);
    return (unsigned short)(r >> 16);
}

__device__ __forceinline__ void gld_lds16(const void* g, void* l) {
    __builtin_amdgcn_global_load_lds(
        (const __attribute__((address_space(1))) void*)g,
        (__attribute__((address_space(3))) void*)l, 16, 0, 0);
}

// numpy pairwise sum of squares, n=256, bitwise-faithful (verified rounds 2-5).
__device__ float np_sumsq_256(const float* __restrict__ p) {
#pragma clang fp contract(off)
    float blk[2];
    #pragma unroll
    for (int b = 0; b < 2; ++b) {
        const float* q = p + b * 128;
        float r[8];
        #pragma unroll
        for (int j = 0; j < 8; ++j) r[j] = __fmul_rn(q[j], q[j]);
        for (int i = 8; i < 128; i += 8) {
            #pragma unroll
            for (int j = 0; j < 8; ++j)
                r[j] = __fadd_rn(r[j], __fmul_rn(q[i + j], q[i + j]));
        }
        blk[b] = __fadd_rn(
            __fadd_rn(__fadd_rn(r[0], r[1]), __fadd_rn(r[2], r[3])),
            __fadd_rn(__fadd_rn(r[4], r[5]), __fadd_rn(r[6], r[7])));
    }
    return __fadd_rn(blk[0], blk[1]);
}

__global__ void vq_sumsq_kernel(const float* __restrict__ a,
                                float* __restrict__ out, int nrows) {
    int r = blockIdx.x * blockDim.x + threadIdx.x;
    if (r < nrows) out[r] = np_sumsq_256(a + (size_t)r * DIM);
}

__global__ void vq_init_kernel(unsigned* __restrict__ cnt, unsigned* __restrict__ ovc) {
    int i = blockIdx.x * 256 + threadIdx.x;
    if (i < NROWS) cnt[i] = 0;
    if (i == 0) *ovc = 0;
}

// A image: [blk 256][wr 2][m 4][kk 8][lane 64] x 16B. Lane's 8 bf16 =
// z[blk*128+wr*64+m*16+(lane&15)][kk*32+(lane>>4)*8 .. +8)
__global__ void vq_cvtA_kernel(const float* __restrict__ z, uint4* __restrict__ zhsw) {
    int t = blockIdx.x * 256 + threadIdx.x;       // 0..1048575
    int lane = t & 63, kk = (t >> 6) & 7, m = (t >> 9) & 3, wr = (t >> 11) & 1, b = t >> 12;
    int row = b * 128 + wr * 64 + m * 16 + (lane & 15);
    int k0  = kk * 32 + (lane >> 4) * 8;
    const float* src = &z[(size_t)row * DIM + k0];
    float4 v0 = *reinterpret_cast<const float4*>(src);
    float4 v1 = *reinterpret_cast<const float4*>(src + 4);
    uint4 o;
    o.x = (unsigned)bf16rne(v0.x) | ((unsigned)bf16rne(v0.y) << 16);
    o.y = (unsigned)bf16rne(v0.z) | ((unsigned)bf16rne(v0.w) << 16);
    o.z = (unsigned)bf16rne(v1.x) | ((unsigned)bf16rne(v1.y) << 16);
    o.w = (unsigned)bf16rne(v1.z) | ((unsigned)bf16rne(v1.w) << 16);
    zhsw[t] = o;
}

// B image: [ct 64][kk 8][cc 128][64B row]; byte-in-row = (lhi*16)^((cc&3)<<4)
// holds cb[ct*128+cc][kk*32+lhi*8 .. +8) as bf16. Linear global_load_lds then
// swizzled ds_read_b128 is bank-uniform.
__global__ void vq_cvtB_kernel(const float* __restrict__ cb, uint4* __restrict__ cbsw) {
    int t = blockIdx.x * 256 + threadIdx.x;       // 0..262143
    int s4 = t & 3, cc = (t >> 2) & 127, kk = (t >> 9) & 7, ct = t >> 12;
    int lhi = s4 ^ (cc & 3);
    int k0 = kk * 32 + lhi * 8;
    const float* src = &cb[(size_t)(ct * 128 + cc) * DIM + k0];
    float4 v0 = *reinterpret_cast<const float4*>(src);
    float4 v1 = *reinterpret_cast<const float4*>(src + 4);
    uint4 o;
    o.x = (unsigned)bf16rne(v0.x) | ((unsigned)bf16rne(v0.y) << 16);
    o.y = (unsigned)bf16rne(v0.z) | ((unsigned)bf16rne(v0.w) << 16);
    o.z = (unsigned)bf16rne(v1.x) | ((unsigned)bf16rne(v1.y) << 16);
    o.w = (unsigned)bf16rne(v1.z) | ((unsigned)bf16rne(v1.w) << 16);
    cbsw[t] = o;
}

// ---------------- MFMA screen (structure identical to passing round 5) ------
__global__ __launch_bounds__(512, 2) void vq_screen_kernel(
    const uint4* __restrict__ zhsw, const char* __restrict__ cbsw,
    const float* __restrict__ zsq, const float* __restrict__ csq,
    unsigned* __restrict__ cnt, unsigned short* __restrict__ cand) {
    __shared__ __align__(16) unsigned char Bbuf[2][65536];
    __shared__ float runmin[128];
    const int tid = threadIdx.x, lane = tid & 63, wid = tid >> 6;
    const int wr = wid >> 2, wc = wid & 3;
    const int l15 = lane & 15, lhi = lane >> 4;
    const int b = blockIdx.x, row0 = b * 128;

    bf16x8 ah[4][8];
    {
        const uint4* abase = zhsw + (size_t)b * 4096 + wr * 2048 + lane;
        #pragma unroll
        for (int m = 0; m < 4; ++m)
            #pragma unroll
            for (int kk = 0; kk < 8; ++kk)
                ah[m][kk] = __builtin_bit_cast(bf16x8, abase[m * 512 + kk * 64]);
    }

    float Zr[4][4];
    #pragma unroll
    for (int m = 0; m < 4; ++m) {
        float4 zq = *reinterpret_cast<const float4*>(&zsq[row0 + wr * 64 + m * 16 + lhi * 4]);
        Zr[m][0] = zq.x; Zr[m][1] = zq.y; Zr[m][2] = zq.z; Zr[m][3] = zq.w;
    }

    f32x4 acc[4][2];
    auto ZERO = [&]() {
        #pragma unroll
        for (int m = 0; m < 4; ++m)
            #pragma unroll
            for (int n = 0; n < 2; ++n) acc[m][n] = (f32x4){0.f, 0.f, 0.f, 0.f};
    };
    ZERO();

    auto STAGE = [&](int buf, int ct2) {
        const char* g = cbsw + (size_t)ct2 * 65536 + wid * 8192 + lane * 16;
        unsigned char* l = &Bbuf[buf][wid * 8192];
        #pragma unroll
        for (int i = 0; i < 8; ++i)
            gld_lds16(g + i * 1024, l + i * 1024);
    };

    auto MFMA = [&](int buf) {
        const int cc0 = wc * 32 + l15, cc1 = cc0 + 16;
        const int sw0 = (lhi * 16) ^ ((cc0 & 3) << 4);
        const int sw1 = (lhi * 16) ^ ((cc1 & 3) << 4);
        #pragma unroll
        for (int kk = 0; kk < 8; ++kk) {
            bf16x8 bh0 = *reinterpret_cast<const bf16x8*>(&Bbuf[buf][kk * 8192 + cc0 * 64 + sw0]);
            bf16x8 bh1 = *reinterpret_cast<const bf16x8*>(&Bbuf[buf][kk * 8192 + cc1 * 64 + sw1]);
            #pragma unroll
            for (int m = 0; m < 4; ++m) {
                acc[m][0] = __builtin_amdgcn_mfma_f32_16x16x32_bf16(ah[m][kk], bh0, acc[m][0], 0, 0, 0);
                acc[m][1] = __builtin_amdgcn_mfma_f32_16x16x32_bf16(ah[m][kk], bh1, acc[m][1], 0, 0, 0);
            }
        }
    };

    auto EPI = [&](int ct, bool collect) {
        float cs0 = csq[ct * 128 + wc * 32 + l15];
        float cs1 = csq[ct * 128 + wc * 32 + 16 + l15];
        #pragma unroll
        for (int m = 0; m < 4; ++m) {
            float4 rmv = *reinterpret_cast<const float4*>(&runmin[wr * 64 + m * 16 + lhi * 4]);
            #pragma unroll
            for (int r = 0; r < 4; ++r) {
                const float rm = (r == 0) ? rmv.x : (r == 1) ? rmv.y : (r == 2) ? rmv.z : rmv.w;
                const int lr = wr * 64 + m * 16 + lhi * 4 + r;
                #pragma unroll
                for (int n = 0; n < 2; ++n) {
                    float s = __fadd_rn(__fsub_rn(Zr[m][r], __fmul_rn(2.0f, acc[m][n][r])),
                                        n ? cs1 : cs0);
                    if (s < rm)
                        atomicMin((unsigned*)&runmin[lr], __float_as_uint(s));
                    if (collect && s < rm + MARGIN) {
                        int grow = row0 + lr;
                        unsigned slot = atomicAdd(&cnt[grow], 1u);
                        if (slot < CANDCAP)
                            cand[(size_t)grow * CANDCAP + slot] =
                                (unsigned short)(ct * 128 + wc * 32 + n * 16 + l15);
                    }
                }
            }
        }
    };

    STAGE(0, 0);
    if (tid < 128) runmin[tid] = 3.4e38f;
    __syncthreads();

    STAGE(1, 1);
    MFMA(0);
    EPI(0, false);
    __syncthreads();
    EPI(0, true);
    ZERO();
    __syncthreads();

    for (int ct = 1; ct < 64; ++ct) {
        const int buf = ct & 1;
        if (ct < 63) STAGE(buf ^ 1, ct + 1);
        MFMA(buf);
        EPI(ct, true);
        ZERO();
        __syncthreads();
    }
}

// ---------------- exact resolve ----------------
// One wave per row; lanes sweep the candidate list with the bitwise round-2
// chain. Overflow/empty rows -> overflow list for vq_cleanup (no in-kernel
// full scan: scattered full scans were the round-5 1 ms tail).
__global__ __launch_bounds__(256) void vq_exact_kernel(
    const float* __restrict__ z, const float* __restrict__ cb,
    const float* __restrict__ zsq, const float* __restrict__ csq,
    const unsigned* __restrict__ cnt, const unsigned short* __restrict__ cand,
    unsigned* __restrict__ ovl, unsigned* __restrict__ ovc,
    float* __restrict__ idxF) {
    __shared__ float zrow[4][DIM];
    const int wid = threadIdx.x >> 6, lane = threadIdx.x & 63;
    const int row = blockIdx.x * 4 + wid;

    float4 zv4 = *reinterpret_cast<const float4*>(&z[(size_t)row * DIM + lane * 4]);
    *reinterpret_cast<float4*>(&zrow[wid][lane * 4]) = zv4;
    __syncthreads();

    const unsigned c = cnt[row];
    if (c == 0 || c > CANDCAP) {
        if (lane == 0) { unsigned s = atomicAdd(ovc, 1u); ovl[s] = row; }
        return;
    }

    const float Zr = zsq[row];
    const float4* cb4 = reinterpret_cast<const float4*>(cb);
    float best = 3.4e38f;
    int   bi   = 0x7FFFFFFF;

    for (int j = lane; j < (int)c; j += 64) {
        int k = cand[(size_t)row * CANDCAP + j];
        float a = 0.0f;
        #pragma unroll 8
        for (int q = 0; q < 64; ++q) {
            float4 cv = cb4[(size_t)k * 64 + q];
            float4 zv = *reinterpret_cast<const float4*>(&zrow[wid][q * 4]);
            a = fmaf(zv.x, cv.x, a); a = fmaf(zv.y, cv.y, a);
            a = fmaf(zv.z, cv.z, a); a = fmaf(zv.w, cv.w, a);
        }
        float sv = __fadd_rn(__fsub_rn(Zr, __fmul_rn(2.0f, a)), csq[k]);
        if (sv < best || (sv == best && k < bi)) { best = sv; bi = k; }
    }
    #pragma unroll
    for (int mk = 32; mk >= 1; mk >>= 1) {
        float ov = __shfl_xor(best, mk);
        int   oi = __shfl_xor(bi, mk);
        if (ov < best || (ov == best && oi < bi)) { best = ov; bi = oi; }
    }
    if (lane == 0) idxF[row] = (float)bi;
}

// Full scan for overflow rows (expected count: 0). Same bitwise chain,
// first-index tie-break. Grid-strided; exits immediately when list is empty.
__global__ __launch_bounds__(256) void vq_cleanup_kernel(
    const float* __restrict__ z, const float* __restrict__ cb,
    const float* __restrict__ zsq, const float* __restrict__ csq,
    const unsigned* __restrict__ ovl, const unsigned* __restrict__ ovc,
    float* __restrict__ idxF) {
    __shared__ float zrow[DIM];
    __shared__ float wv[4]; __shared__ int wi[4];
    const int lane = threadIdx.x & 63, wid = threadIdx.x >> 6;
    const unsigned count = *ovc;
    for (unsigned w = blockIdx.x; w < count; w += gridDim.x) {
        const int row = ovl[w];
        __syncthreads();
        *reinterpret_cast<float4*>(&zrow[threadIdx.x * 4 & (DIM - 1)]) =
            *reinterpret_cast<const float4*>(&z[(size_t)row * DIM + (threadIdx.x * 4 & (DIM - 1))]);
        __syncthreads();
        const float Zr = zsq[row];
        const float4* cb4 = reinterpret_cast<const float4*>(cb);
        float best = 3.4e38f; int bi = 0x7FFFFFFF;
        for (int k = threadIdx.x; k < KCB; k += 256) {
            float a = 0.0f;
            #pragma unroll 8
            for (int q = 0; q < 64; ++q) {
                float4 cv = cb4[(size_t)k * 64 + q];
                float4 zv = *reinterpret_cast<const float4*>(&zrow[q * 4]);
                a = fmaf(zv.x, cv.x, a); a = fmaf(zv.y, cv.y, a);
                a = fmaf(zv.z, cv.z, a); a = fmaf(zv.w, cv.w, a);
            }
            float sv = __fadd_rn(__fsub_rn(Zr, __fmul_rn(2.0f, a)), csq[k]);
            if (sv < best || (sv == best && k < bi)) { best = sv; bi = k; }
        }
        #pragma unroll
        for (int mk = 32; mk >= 1; mk >>= 1) {
            float ov = __shfl_xor(best, mk);
            int   oi = __shfl_xor(bi, mk);
            if (ov < best || (ov == best && oi < bi)) { best = ov; bi = oi; }
        }
        if (lane == 0) { wv[wid] = best; wi[wid] = bi; }
        __syncthreads();
        if (threadIdx.x == 0) {
            #pragma unroll
            for (int u = 1; u < 4; ++u)
                if (wv[u] < best || (wv[u] == best && wi[u] < bi)) { best = wv[u]; bi = wi[u]; }
            idxF[row] = (float)bi;
        }
    }
}

__global__ void vq_gather_kernel(const float* __restrict__ cb,
                                 const float* __restrict__ idxF,
                                 float4* __restrict__ out4) {
    int g = blockIdx.x * blockDim.x + threadIdx.x;
    const float4* cb4 = reinterpret_cast<const float4*>(cb);
    for (int i = g; i < NROWS * 64; i += gridDim.x * blockDim.x) {
        int row = i >> 6, q = i & 63;
        int idx = (int)idxF[row];
        out4[i] = cb4[(size_t)idx * 64 + q];
    }
}

extern "C" void kernel_launch(void* const* d_in, const int* in_sizes, int n_in,
                              void* d_out, int out_size, void* d_ws, size_t ws_size,
                              hipStream_t stream) {
    const float* z  = (const float*)d_in[0];
    const float* cb = (const float*)d_in[1];
    float* out = (float*)d_out;

    unsigned short* candp = (unsigned short*)(out + OFF_CAND);
    unsigned*       cntp  = (unsigned*)(out + OFF_CNT);
    float*          zsq   = out + OFF_ZSQ;
    float*          csq   = out + OFF_CSQ;
    unsigned*       ovl   = (unsigned*)(out + OFF_OVL);
    unsigned*       ovc   = (unsigned*)(out + OFF_OVC);
    uint4*          zhsw  = (uint4*)(out + OFF_ZHSW);
    uint4*          cbsw  = (uint4*)(out + OFF_CBSW);
    float*          idxF  = out + OFF_IDX;

    vq_sumsq_kernel<<<KCB / 256, 256, 0, stream>>>(cb, csq, KCB);
    vq_sumsq_kernel<<<NROWS / 256, 256, 0, stream>>>(z, zsq, NROWS);
    vq_init_kernel<<<NROWS / 256, 256, 0, stream>>>(cntp, ovc);
    vq_cvtA_kernel<<<4096, 256, 0, stream>>>(z, zhsw);
    vq_cvtB_kernel<<<1024, 256, 0, stream>>>(cb, cbsw);
    vq_screen_kernel<<<256, 512, 0, stream>>>(zhsw, (const char*)cbsw, zsq, csq, cntp, candp);
    vq_exact_kernel<<<NROWS / 4, 256, 0, stream>>>(z, cb, zsq, csq, cntp, candp, ovl, ovc, idxF);
    vq_cleanup_kernel<<<64, 256, 0, stream>>>(z, cb, zsq, csq, ovl, ovc, idxF);
    vq_gather_kernel<<<2048, 256, 0, stream>>>(cb, idxF, (float4*)out);
}

// Round 7
// 351.572 us; speedup vs baseline: 3.9233x; 1.2474x over previous
//
#include <hip/hip_runtime.h>

// Vector quantization: z [32768,256] f32, codebook [8192,256] f32
// outputs: z_q [32768,256] f32, indices [32768] (as float)
//
// bf16 MFMA screen (margin-bounded candidate superset) + exact resolve with
// the bitwise round-2 f32 chain (absmax 0 in rounds 2-6).
// Screen is barrier-free: per-wave private B tiles, counted s_waitcnt vmcnt(9)
// double-buffer, candidates buffered in LDS and flushed once at the end.

#define NROWS 32768
#define DIM   256
#define KCB   8192
#define CANDCAP 128
#define MARGIN  4.5e-4f
#define WBUF    320
#define NTILE   512      // 8192 / 16 codes per tile
#define RECB    9216     // record bytes: 8 KB frags + 1 KB csq1 chunk

// float-slot offsets into d_out scratch (z_q region; gather overwrites last)
#define OFF_CAND  0          // u16 [32768][128] (8 MB)
#define OFF_CNT   2097152    // u32 [32768]
#define OFF_ZSQ   2129920    // f32 [32768]
#define OFF_CSQ   2162688    // f32 [8192]
#define OFF_OVL   2170880    // u32 [32768] overflow rows
#define OFF_OVC   2203648    // u32 overflow count (+pad)
#define OFF_IMG   2203664    // B tile image, 512 * 9216 B (16B-aligned)
#define OFF_IDX   8388608    // final indices (float) - real output tail

using bf16x8 = __attribute__((ext_vector_type(8))) short;
using f32x4  = __attribute__((ext_vector_type(4))) float;

__device__ __forceinline__ unsigned short bf16rne(float f) {
    unsigned u = __float_as_uint(f);
    unsigned r = u + 0x7FFFu + ((u >> 16) & 1u);
    return (unsigned short)(r >> 16);
}

__device__ __forceinline__ void gld_lds16(const void* g, void* l) {
    __builtin_amdgcn_global_load_lds(
        (const __attribute__((address_space(1))) void*)g,
        (__attribute__((address_space(3))) void*)l, 16, 0, 0);
}

// numpy pairwise sum of squares, n=256, bitwise-faithful (verified rounds 2-6).
__device__ float np_sumsq_256(const float* __restrict__ p) {
#pragma clang fp contract(off)
    float blk[2];
    #pragma unroll
    for (int b = 0; b < 2; ++b) {
        const float* q = p + b * 128;
        float r[8];
        #pragma unroll
        for (int j = 0; j < 8; ++j) r[j] = __fmul_rn(q[j], q[j]);
        for (int i = 8; i < 128; i += 8) {
            #pragma unroll
            for (int j = 0; j < 8; ++j)
                r[j] = __fadd_rn(r[j], __fmul_rn(q[i + j], q[i + j]));
        }
        blk[b] = __fadd_rn(
            __fadd_rn(__fadd_rn(r[0], r[1]), __fadd_rn(r[2], r[3])),
            __fadd_rn(__fadd_rn(r[4], r[5]), __fadd_rn(r[6], r[7])));
    }
    return __fadd_rn(blk[0], blk[1]);
}

__global__ void vq_sumsq2_kernel(const float* __restrict__ z,
                                 const float* __restrict__ cb,
                                 float* __restrict__ zsq, float* __restrict__ csq) {
    int r = blockIdx.x * 256 + threadIdx.x;
    if (r < NROWS) zsq[r] = np_sumsq_256(z + (size_t)r * DIM);
    else if (r < NROWS + KCB) csq[r - NROWS] = np_sumsq_256(cb + (size_t)(r - NROWS) * DIM);
}

// Build B tile image + init counters. Record T (tile of 16 codes):
//  bytes [kk*1024 + s*16]: s=(code<<2)|lhi -> bf16 of cb[T*16+code][kk*32+lhi*8..+8)
//  bytes [8192 .. 8256): 16 f32 = csq[T*16..+16] + 1.0   (rest of chunk: pad)
__global__ void vq_prepB_kernel(const float* __restrict__ cb,
                                const float* __restrict__ csq,
                                char* __restrict__ img,
                                unsigned* __restrict__ cnt, unsigned* __restrict__ ovc) {
    int t = blockIdx.x * 256 + threadIdx.x;
    if (t < NROWS) cnt[t] = 0;
    if (t == 0) *ovc = 0;
    if (t < 262144) {
        int s = t & 63, kk = (t >> 6) & 7, T = t >> 9;
        int code = T * 16 + (s >> 2), lhi = s & 3;
        const float* src = cb + (size_t)code * DIM + kk * 32 + lhi * 8;
        float4 v0 = *reinterpret_cast<const float4*>(src);
        float4 v1 = *reinterpret_cast<const float4*>(src + 4);
        uint4 o;
        o.x = (unsigned)bf16rne(v0.x) | ((unsigned)bf16rne(v0.y) << 16);
        o.y = (unsigned)bf16rne(v0.z) | ((unsigned)bf16rne(v0.w) << 16);
        o.z = (unsigned)bf16rne(v1.x) | ((unsigned)bf16rne(v1.y) << 16);
        o.w = (unsigned)bf16rne(v1.z) | ((unsigned)bf16rne(v1.w) << 16);
        *reinterpret_cast<uint4*>(img + (size_t)T * RECB + kk * 1024 + s * 16) = o;
    } else {
        int t2 = t - 262144;                  // 0..2047
        if (t2 < NTILE * 4) {
            int T = t2 >> 2, q = t2 & 3;
            float4 c = *reinterpret_cast<const float4*>(&csq[T * 16 + q * 4]);
            c.x += 1.0f; c.y += 1.0f; c.z += 1.0f; c.w += 1.0f;
            *reinterpret_cast<float4*>(img + (size_t)T * RECB + 8192 + q * 16) = c;
        }
    }
}

// ---------------- barrier-free MFMA screen ----------------
// Grid 256 x 512 thr (8 waves). Wave w: rows (w>>2)*64..+64 of the block's 128,
// codes (w&3)*2048..+2048 as 128 private 16-code tiles, double-buffered.
// Per-wave sync only: s_waitcnt vmcnt(9). One __syncthreads at kernel start.
__global__ __launch_bounds__(512, 1) void vq_screen_kernel(
    const float* __restrict__ z, const char* __restrict__ img,
    unsigned* __restrict__ cnt, unsigned short* __restrict__ cand) {
    __shared__ __align__(16) unsigned char Bpriv[8][2][RECB];   // 147456 B
    __shared__ unsigned runmin[128];
    __shared__ unsigned wcnt[8];
    __shared__ unsigned wbuf[8][WBUF];                           // 10240 B
    const int tid = threadIdx.x, lane = tid & 63, wid = tid >> 6;
    const int wr = wid >> 2, wc = wid & 3;
    const int l15 = lane & 15, lhi = lane >> 4;
    const int row0 = blockIdx.x * 128;
    const int tbase = wc * 128;
    unsigned char* myB = &Bpriv[wid][0][0];

    // A fragments from raw z (one-time inline bf16 convert)
    bf16x8 ah[4][8];
    #pragma unroll
    for (int m = 0; m < 4; ++m) {
        const float* zr = z + (size_t)(row0 + wr * 64 + m * 16 + l15) * DIM;
        #pragma unroll
        for (int kk = 0; kk < 8; ++kk) {
            float4 v0 = *reinterpret_cast<const float4*>(zr + kk * 32 + lhi * 8);
            float4 v1 = *reinterpret_cast<const float4*>(zr + kk * 32 + lhi * 8 + 4);
            uint4 o;
            o.x = (unsigned)bf16rne(v0.x) | ((unsigned)bf16rne(v0.y) << 16);
            o.y = (unsigned)bf16rne(v0.z) | ((unsigned)bf16rne(v0.w) << 16);
            o.z = (unsigned)bf16rne(v1.x) | ((unsigned)bf16rne(v1.y) << 16);
            o.w = (unsigned)bf16rne(v1.z) | ((unsigned)bf16rne(v1.w) << 16);
            ah[m][kk] = __builtin_bit_cast(bf16x8, o);
        }
    }

    if (tid < 128) runmin[tid] = 0x7F800000u;   // +inf (s'' > 0 -> uint-monotone)
    if (tid < 8) wcnt[tid] = 0;
    __syncthreads();                            // the only block barrier

    f32x4 acc[4];
    #pragma unroll
    for (int m = 0; m < 4; ++m) acc[m] = (f32x4){0.f, 0.f, 0.f, 0.f};

    auto STAGE = [&](int buf, int ct) {
        const char* g = img + (size_t)(tbase + ct) * RECB + lane * 16;
        unsigned char* l = myB + buf * RECB;
        #pragma unroll
        for (int i = 0; i < 9; ++i)
            gld_lds16(g + i * 1024, l + i * 1024);
    };

    auto PUSH = [&](int lr, int code) {
        unsigned pi = atomicAdd(&wcnt[wid], 1u);
        if (pi < WBUF) wbuf[wid][pi] = ((unsigned)lr << 13) | (unsigned)code;
        else {
            int grow = row0 + lr;
            unsigned gs = atomicAdd(&cnt[grow], 1u);
            if (gs < CANDCAP) cand[(size_t)grow * CANDCAP + gs] = (unsigned short)code;
        }
    };

    STAGE(0, 0);

    for (int ct = 0; ct < 128; ++ct) {
        const int buf = ct & 1;
        if (ct < 127) {
            STAGE(buf ^ 1, ct + 1);
            asm volatile("s_waitcnt vmcnt(9)" ::: "memory");
        } else {
            asm volatile("s_waitcnt vmcnt(0)" ::: "memory");
        }
        const unsigned char* mb = myB + buf * RECB;
        const float cs1 = *reinterpret_cast<const float*>(mb + 8192 + l15 * 4);
        __builtin_amdgcn_s_setprio(1);
        #pragma unroll
        for (int kk = 0; kk < 8; ++kk) {
            bf16x8 bh = *reinterpret_cast<const bf16x8*>(mb + kk * 1024 + l15 * 64 + lhi * 16);
            #pragma unroll
            for (int m = 0; m < 4; ++m)
                acc[m] = __builtin_amdgcn_mfma_f32_16x16x32_bf16(ah[m][kk], bh, acc[m], 0, 0, 0);
        }
        __builtin_amdgcn_s_setprio(0);

        const int codeb = (tbase + ct) * 16 + l15;
        if (ct == 0) {
            // self-bound first tile (runmin may still be +inf): bound = tile min
            #pragma unroll
            for (int m = 0; m < 4; ++m) {
                const int lr0 = wr * 64 + m * 16 + lhi * 4;
                #pragma unroll
                for (int r = 0; r < 4; ++r) {
                    float s2 = fmaf(acc[m][r], -2.0f, cs1);
                    float sm = s2;
                    sm = fminf(sm, __shfl_xor(sm, 1));
                    sm = fminf(sm, __shfl_xor(sm, 2));
                    sm = fminf(sm, __shfl_xor(sm, 4));
                    sm = fminf(sm, __shfl_xor(sm, 8));
                    if (l15 == 0) atomicMin(&runmin[lr0 + r], __float_as_uint(sm));
                    if (s2 < sm + MARGIN) PUSH(lr0 + r, codeb);
                }
                acc[m] = (f32x4){0.f, 0.f, 0.f, 0.f};
            }
        } else {
            #pragma unroll
            for (int m = 0; m < 4; ++m) {
                const int lr0 = wr * 64 + m * 16 + lhi * 4;
                uint4 rmb = *reinterpret_cast<const uint4*>(&runmin[lr0]);
                #pragma unroll
                for (int r = 0; r < 4; ++r) {
                    float s2 = fmaf(acc[m][r], -2.0f, cs1);
                    const unsigned rmu = (r == 0) ? rmb.x : (r == 1) ? rmb.y
                                        : (r == 2) ? rmb.z : rmb.w;
                    const float rm = __uint_as_float(rmu);
                    const bool cf = s2 < rm + MARGIN;
                    if (__any(cf)) {
                        if (cf) {
                            if (s2 < rm) atomicMin(&runmin[lr0 + r], __float_as_uint(s2));
                            PUSH(lr0 + r, codeb);
                        }
                    }
                }
                acc[m] = (f32x4){0.f, 0.f, 0.f, 0.f};
            }
        }
    }

    // flush wave-local candidate buffer to global per-row lists
    unsigned n = wcnt[wid]; if (n > WBUF) n = WBUF;
    for (unsigned e = lane; e < n; e += 64) {
        unsigned u = wbuf[wid][e];
        int row = row0 + (int)(u >> 13);
        int code = (int)(u & 8191u);
        unsigned slot = atomicAdd(&cnt[row], 1u);
        if (slot < CANDCAP) cand[(size_t)row * CANDCAP + slot] = (unsigned short)code;
    }
}

// ---------------- exact resolve (verbatim from passing round 6) ----------------
__global__ __launch_bounds__(256) void vq_exact_kernel(
    const float* __restrict__ z, const float* __restrict__ cb,
    const float* __restrict__ zsq, const float* __restrict__ csq,
    const unsigned* __restrict__ cnt, const unsigned short* __restrict__ cand,
    unsigned* __restrict__ ovl, unsigned* __restrict__ ovc,
    float* __restrict__ idxF) {
    __shared__ float zrow[4][DIM];
    const int wid = threadIdx.x >> 6, lane = threadIdx.x & 63;
    const int row = blockIdx.x * 4 + wid;

    float4 zv4 = *reinterpret_cast<const float4*>(&z[(size_t)row * DIM + lane * 4]);
    *reinterpret_cast<float4*>(&zrow[wid][lane * 4]) = zv4;
    __syncthreads();

    const unsigned c = cnt[row];
    if (c == 0 || c > CANDCAP) {
        if (lane == 0) { unsigned s = atomicAdd(ovc, 1u); ovl[s] = row; }
        return;
    }

    const float Zr = zsq[row];
    const float4* cb4 = reinterpret_cast<const float4*>(cb);
    float best = 3.4e38f;
    int   bi   = 0x7FFFFFFF;

    for (int j = lane; j < (int)c; j += 64) {
        int k = cand[(size_t)row * CANDCAP + j];
        float a = 0.0f;
        #pragma unroll 8
        for (int q = 0; q < 64; ++q) {
            float4 cv = cb4[(size_t)k * 64 + q];
            float4 zv = *reinterpret_cast<const float4*>(&zrow[wid][q * 4]);
            a = fmaf(zv.x, cv.x, a); a = fmaf(zv.y, cv.y, a);
            a = fmaf(zv.z, cv.z, a); a = fmaf(zv.w, cv.w, a);
        }
        float sv = __fadd_rn(__fsub_rn(Zr, __fmul_rn(2.0f, a)), csq[k]);
        if (sv < best || (sv == best && k < bi)) { best = sv; bi = k; }
    }
    #pragma unroll
    for (int mk = 32; mk >= 1; mk >>= 1) {
        float ov = __shfl_xor(best, mk);
        int   oi = __shfl_xor(bi, mk);
        if (ov < best || (ov == best && oi < bi)) { best = ov; bi = oi; }
    }
    if (lane == 0) idxF[row] = (float)bi;
}

// Full scan for overflow rows (expected 0). Bitwise chain, first-index ties.
__global__ __launch_bounds__(256) void vq_cleanup_kernel(
    const float* __restrict__ z, const float* __restrict__ cb,
    const float* __restrict__ zsq, const float* __restrict__ csq,
    const unsigned* __restrict__ ovl, const unsigned* __restrict__ ovc,
    float* __restrict__ idxF) {
    __shared__ float zrow[DIM];
    __shared__ float wv[4]; __shared__ int wi[4];
    const int lane = threadIdx.x & 63, wid = threadIdx.x >> 6;
    const unsigned count = *ovc;
    for (unsigned w = blockIdx.x; w < count; w += gridDim.x) {
        const int row = ovl[w];
        __syncthreads();
        *reinterpret_cast<float4*>(&zrow[threadIdx.x * 4 & (DIM - 1)]) =
            *reinterpret_cast<const float4*>(&z[(size_t)row * DIM + (threadIdx.x * 4 & (DIM - 1))]);
        __syncthreads();
        const float Zr = zsq[row];
        const float4* cb4 = reinterpret_cast<const float4*>(cb);
        float best = 3.4e38f; int bi = 0x7FFFFFFF;
        for (int k = threadIdx.x; k < KCB; k += 256) {
            float a = 0.0f;
            #pragma unroll 8
            for (int q = 0; q < 64; ++q) {
                float4 cv = cb4[(size_t)k * 64 + q];
                float4 zv = *reinterpret_cast<const float4*>(&zrow[q * 4]);
                a = fmaf(zv.x, cv.x, a); a = fmaf(zv.y, cv.y, a);
                a = fmaf(zv.z, cv.z, a); a = fmaf(zv.w, cv.w, a);
            }
            float sv = __fadd_rn(__fsub_rn(Zr, __fmul_rn(2.0f, a)), csq[k]);
            if (sv < best || (sv == best && k < bi)) { best = sv; bi = k; }
        }
        #pragma unroll
        for (int mk = 32; mk >= 1; mk >>= 1) {
            float ov = __shfl_xor(best, mk);
            int   oi = __shfl_xor(bi, mk);
            if (ov < best || (ov == best && oi < bi)) { best = ov; bi = oi; }
        }
        if (lane == 0) { wv[wid] = best; wi[wid] = bi; }
        __syncthreads();
        if (threadIdx.x == 0) {
            #pragma unroll
            for (int u = 1; u < 4; ++u)
                if (wv[u] < best || (wv[u] == best && wi[u] < bi)) { best = wv[u]; bi = wi[u]; }
            idxF[row] = (float)bi;
        }
    }
}

__global__ void vq_gather_kernel(const float* __restrict__ cb,
                                 const float* __restrict__ idxF,
                                 float4* __restrict__ out4) {
    int g = blockIdx.x * blockDim.x + threadIdx.x;
    const float4* cb4 = reinterpret_cast<const float4*>(cb);
    for (int i = g; i < NROWS * 64; i += gridDim.x * blockDim.x) {
        int row = i >> 6, q = i & 63;
        int idx = (int)idxF[row];
        out4[i] = cb4[(size_t)idx * 64 + q];
    }
}

extern "C" void kernel_launch(void* const* d_in, const int* in_sizes, int n_in,
                              void* d_out, int out_size, void* d_ws, size_t ws_size,
                              hipStream_t stream) {
    const float* z  = (const float*)d_in[0];
    const float* cb = (const float*)d_in[1];
    float* out = (float*)d_out;

    unsigned short* candp = (unsigned short*)(out + OFF_CAND);
    unsigned*       cntp  = (unsigned*)(out + OFF_CNT);
    float*          zsq   = out + OFF_ZSQ;
    float*          csq   = out + OFF_CSQ;
    unsigned*       ovl   = (unsigned*)(out + OFF_OVL);
    unsigned*       ovc   = (unsigned*)(out + OFF_OVC);
    char*           img   = (char*)(out + OFF_IMG);
    float*          idxF  = out + OFF_IDX;

    vq_sumsq2_kernel<<<(NROWS + KCB) / 256, 256, 0, stream>>>(z, cb, zsq, csq);
    vq_prepB_kernel<<<1032, 256, 0, stream>>>(cb, csq, img, cntp, ovc);
    vq_screen_kernel<<<NROWS / 128, 512, 0, stream>>>(z, img, cntp, candp);
    vq_exact_kernel<<<NROWS / 4, 256, 0, stream>>>(z, cb, zsq, csq, cntp, candp, ovl, ovc, idxF);
    vq_cleanup_kernel<<<64, 256, 0, stream>>>(z, cb, zsq, csq, ovl, ovc, idxF);
    vq_gather_kernel<<<2048, 256, 0, stream>>>(cb, idxF, (float4*)out);
}

// Round 8
// 298.969 us; speedup vs baseline: 4.6136x; 1.1759x over previous
//
#include <hip/hip_runtime.h>

// Vector quantization: z [32768,256] f32, codebook [8192,256] f32
// outputs: z_q [32768,256] f32, indices [32768] (as float)
//
// bf16 MFMA screen (margin-bounded candidate superset) + exact resolve with
// the bitwise round-2 f32 chain (absmax 0 in rounds 2-7).
// Screen v3: B tiles stream global -> REGISTERS (no LDS staging, no barriers,
// no ds_read in the K-loop). Named double-buffered register tiles, natural
// compiler vmcnt pipelining.

#define NROWS 32768
#define DIM   256
#define KCB   8192
#define CANDCAP 128
#define MARGIN  4.5e-4f
#define WBUF    320
#define NTILE   512      // 8192 codes / 16 per tile

// float-slot offsets into d_out scratch (z_q region; gather overwrites last)
#define OFF_CAND  0          // u16 [32768][128] (8 MB)
#define OFF_CNT   2097152    // u32 [32768]
#define OFF_ZSQ   2129920    // f32 [32768]
#define OFF_CSQ   2162688    // f32 [8192]
#define OFF_CSQ1  2170880    // f32 [8192]  csq + 1.0 (screen epilogue constant)
#define OFF_OVL   2179072    // u32 [32768] overflow rows
#define OFF_OVC   2211840    // u32 overflow count (+pad to 16 slots)
#define OFF_IMG   2211856    // B tile image [512][8][64]x16B = 4 MB (16B-aligned)
#define OFF_IDX   8388608    // final indices (float) - real output tail

using bf16x8 = __attribute__((ext_vector_type(8))) short;
using f32x4  = __attribute__((ext_vector_type(4))) float;

__device__ __forceinline__ unsigned short bf16rne(float f) {
    unsigned u = __float_as_uint(f);
    unsigned r = u + 0x7FFFu + ((u >> 16) & 1u);
    return (unsigned short)(r >> 16);
}

// numpy pairwise sum of squares, n=256, bitwise-faithful (verified rounds 2-7).
__device__ float np_sumsq_256(const float* __restrict__ p) {
#pragma clang fp contract(off)
    float blk[2];
    #pragma unroll
    for (int b = 0; b < 2; ++b) {
        const float* q = p + b * 128;
        float r[8];
        #pragma unroll
        for (int j = 0; j < 8; ++j) r[j] = __fmul_rn(q[j], q[j]);
        for (int i = 8; i < 128; i += 8) {
            #pragma unroll
            for (int j = 0; j < 8; ++j)
                r[j] = __fadd_rn(r[j], __fmul_rn(q[i + j], q[i + j]));
        }
        blk[b] = __fadd_rn(
            __fadd_rn(__fadd_rn(r[0], r[1]), __fadd_rn(r[2], r[3])),
            __fadd_rn(__fadd_rn(r[4], r[5]), __fadd_rn(r[6], r[7])));
    }
    return __fadd_rn(blk[0], blk[1]);
}

__global__ void vq_sumsq2_kernel(const float* __restrict__ z,
                                 const float* __restrict__ cb,
                                 float* __restrict__ zsq, float* __restrict__ csq) {
    int r = blockIdx.x * 256 + threadIdx.x;
    if (r < NROWS) zsq[r] = np_sumsq_256(z + (size_t)r * DIM);
    else if (r < NROWS + KCB) csq[r - NROWS] = np_sumsq_256(cb + (size_t)(r - NROWS) * DIM);
}

// B image: [T 512][kk 8][s 64] x 16B; s = lhi*16 + code, content = bf16x8 of
// cb[T*16+code][kk*32+lhi*8 .. +8).  A wave's 8 dwordx4 at (T*8192 + lane*16
// + kk*1024) are exactly its MFMA B-fragments, each load 1KB coalesced.
__global__ void vq_prepB_kernel(const float* __restrict__ cb,
                                const float* __restrict__ csq,
                                char* __restrict__ img, float* __restrict__ csq1,
                                unsigned* __restrict__ cnt, unsigned* __restrict__ ovc) {
    int t = blockIdx.x * 256 + threadIdx.x;
    if (t < NROWS) cnt[t] = 0;
    if (t == 0) *ovc = 0;
    if (t < 262144) {
        int s = t & 63, kk = (t >> 6) & 7, T = t >> 9;
        int code = s & 15, lhi = s >> 4;
        const float* src = cb + (size_t)(T * 16 + code) * DIM + kk * 32 + lhi * 8;
        float4 v0 = *reinterpret_cast<const float4*>(src);
        float4 v1 = *reinterpret_cast<const float4*>(src + 4);
        uint4 o;
        o.x = (unsigned)bf16rne(v0.x) | ((unsigned)bf16rne(v0.y) << 16);
        o.y = (unsigned)bf16rne(v0.z) | ((unsigned)bf16rne(v0.w) << 16);
        o.z = (unsigned)bf16rne(v1.x) | ((unsigned)bf16rne(v1.y) << 16);
        o.w = (unsigned)bf16rne(v1.z) | ((unsigned)bf16rne(v1.w) << 16);
        *reinterpret_cast<uint4*>(img + (size_t)T * 8192 + kk * 1024 + s * 16) = o;
    } else if (t < 262144 + KCB) {
        csq1[t - 262144] = csq[t - 262144] + 1.0f;
    }
}

// ---------------- register-streamed MFMA screen ----------------
// Grid 256 x 512 thr (8 waves = 2 wr x 4 wc). Wave: 64 rows x 2048 codes as
// 128 16-code tiles. B tile = 8 x dwordx4 per lane, double-buffered in NAMED
// registers; no LDS staging, no loop barriers.
__global__ __launch_bounds__(512, 2) void vq_screen_kernel(
    const float* __restrict__ z, const char* __restrict__ img,
    const float* __restrict__ csq1,
    unsigned* __restrict__ cnt, unsigned short* __restrict__ cand) {
    __shared__ unsigned runmin[128];
    __shared__ unsigned wcnt[8];
    __shared__ unsigned wbuf[8][WBUF];
    const int tid = threadIdx.x, lane = tid & 63, wid = tid >> 6;
    const int wr = wid >> 2, wc = wid & 3;
    const int l15 = lane & 15, lhi = lane >> 4;
    const int row0 = blockIdx.x * 128;
    const int tbase = wc * 128;

    // A fragments (one-time bf16 convert from raw z) -> 128 VGPRs
    bf16x8 ah[4][8];
    #pragma unroll
    for (int m = 0; m < 4; ++m) {
        const float* zr = z + (size_t)(row0 + wr * 64 + m * 16 + l15) * DIM;
        #pragma unroll
        for (int kk = 0; kk < 8; ++kk) {
            float4 v0 = *reinterpret_cast<const float4*>(zr + kk * 32 + lhi * 8);
            float4 v1 = *reinterpret_cast<const float4*>(zr + kk * 32 + lhi * 8 + 4);
            uint4 o;
            o.x = (unsigned)bf16rne(v0.x) | ((unsigned)bf16rne(v0.y) << 16);
            o.y = (unsigned)bf16rne(v0.z) | ((unsigned)bf16rne(v0.w) << 16);
            o.z = (unsigned)bf16rne(v1.x) | ((unsigned)bf16rne(v1.y) << 16);
            o.w = (unsigned)bf16rne(v1.z) | ((unsigned)bf16rne(v1.w) << 16);
            ah[m][kk] = __builtin_bit_cast(bf16x8, o);
        }
    }

    if (tid < 128) runmin[tid] = 0x7F800000u;   // +inf (s'' > 0 -> uint-monotone)
    if (tid < 8) wcnt[tid] = 0;
    __syncthreads();                            // the only block barrier

    f32x4 acc[4];
    #pragma unroll
    for (int m = 0; m < 4; ++m) acc[m] = (f32x4){0.f, 0.f, 0.f, 0.f};

    // walking pointers (advance per tile; one tile over-read at the end stays
    // inside d_out scratch and is never consumed)
    const char*  gp = img + (size_t)tbase * 8192 + (size_t)lane * 16;
    const float* cp = csq1 + tbase * 16 + l15;
    int codeb = tbase * 16 + l15;

    uint4 bA[8]; float csA;
    uint4 bB[8]; float csB;

    auto PUSH = [&](int lr, int code) {
        unsigned pi = atomicAdd(&wcnt[wid], 1u);
        if (pi < WBUF) wbuf[wid][pi] = ((unsigned)lr << 13) | (unsigned)code;
        else {
            int grow = row0 + lr;
            unsigned gs = atomicAdd(&cnt[grow], 1u);
            if (gs < CANDCAP) cand[(size_t)grow * CANDCAP + gs] = (unsigned short)code;
        }
    };

#define LOADR(bh, cs)                                                     \
    {                                                                     \
        _Pragma("unroll")                                                 \
        for (int kk = 0; kk < 8; ++kk)                                    \
            bh[kk] = *reinterpret_cast<const uint4*>(gp + kk * 1024);     \
        cs = *cp;                                                         \
        gp += 8192; cp += 16;                                             \
    }

#define MFMAS(bh)                                                         \
    {                                                                     \
        __builtin_amdgcn_s_setprio(1);                                    \
        _Pragma("unroll")                                                 \
        for (int kk = 0; kk < 8; ++kk) {                                  \
            bf16x8 bhv = __builtin_bit_cast(bf16x8, bh[kk]);              \
            _Pragma("unroll")                                             \
            for (int m = 0; m < 4; ++m)                                   \
                acc[m] = __builtin_amdgcn_mfma_f32_16x16x32_bf16(         \
                    ah[m][kk], bhv, acc[m], 0, 0, 0);                     \
        }                                                                 \
        __builtin_amdgcn_s_setprio(0);                                    \
    }

#define EPI(csv)                                                          \
    {                                                                     \
        _Pragma("unroll")                                                 \
        for (int m = 0; m < 4; ++m) {                                     \
            const int lr0 = wr * 64 + m * 16 + lhi * 4;                   \
            uint4 rmb = *reinterpret_cast<const uint4*>(&runmin[lr0]);    \
            float s0 = fmaf(acc[m][0], -2.0f, csv);                       \
            float s1 = fmaf(acc[m][1], -2.0f, csv);                       \
            float s2 = fmaf(acc[m][2], -2.0f, csv);                       \
            float s3 = fmaf(acc[m][3], -2.0f, csv);                       \
            bool c0 = s0 < __uint_as_float(rmb.x) + MARGIN;               \
            bool c1 = s1 < __uint_as_float(rmb.y) + MARGIN;               \
            bool c2 = s2 < __uint_as_float(rmb.z) + MARGIN;               \
            bool c3 = s3 < __uint_as_float(rmb.w) + MARGIN;               \
            if (__any(c0 | c1 | c2 | c3)) {                               \
                if (c0) { if (s0 < __uint_as_float(rmb.x)) atomicMin(&runmin[lr0 + 0], __float_as_uint(s0)); PUSH(lr0 + 0, codeb); } \
                if (c1) { if (s1 < __uint_as_float(rmb.y)) atomicMin(&runmin[lr0 + 1], __float_as_uint(s1)); PUSH(lr0 + 1, codeb); } \
                if (c2) { if (s2 < __uint_as_float(rmb.z)) atomicMin(&runmin[lr0 + 2], __float_as_uint(s2)); PUSH(lr0 + 2, codeb); } \
                if (c3) { if (s3 < __uint_as_float(rmb.w)) atomicMin(&runmin[lr0 + 3], __float_as_uint(s3)); PUSH(lr0 + 3, codeb); } \
            }                                                             \
            acc[m] = (f32x4){0.f, 0.f, 0.f, 0.f};                         \
        }                                                                 \
        codeb += 16;                                                      \
    }

    // prologue: tile 0 with self-bound epilogue (runmin may still be +inf)
    LOADR(bA, csA);                 // tile 0
    LOADR(bB, csB);                 // tile 1
    MFMAS(bA);
    {
        #pragma unroll
        for (int m = 0; m < 4; ++m) {
            const int lr0 = wr * 64 + m * 16 + lhi * 4;
            #pragma unroll
            for (int r = 0; r < 4; ++r) {
                float s2 = fmaf(acc[m][r], -2.0f, csA);
                float sm = s2;
                sm = fminf(sm, __shfl_xor(sm, 1));
                sm = fminf(sm, __shfl_xor(sm, 2));
                sm = fminf(sm, __shfl_xor(sm, 4));
                sm = fminf(sm, __shfl_xor(sm, 8));
                if (l15 == 0) atomicMin(&runmin[lr0 + r], __float_as_uint(sm));
                if (s2 < sm + MARGIN) PUSH(lr0 + r, codeb);
            }
            acc[m] = (f32x4){0.f, 0.f, 0.f, 0.f};
        }
        codeb += 16;
    }
    LOADR(bA, csA);                 // tile 2
    MFMAS(bB);
    EPI(csB);                       // tile 1

    for (int ct = 2; ct < 128; ct += 2) {
        LOADR(bB, csB);             // tile ct+1
        MFMAS(bA);
        EPI(csA);                   // tile ct
        LOADR(bA, csA);             // tile ct+2 (ct=126: over-read, unused)
        MFMAS(bB);
        EPI(csB);                   // tile ct+1
    }

    // flush wave-local candidate buffer to global per-row lists
    unsigned n = wcnt[wid]; if (n > WBUF) n = WBUF;
    for (unsigned e = lane; e < n; e += 64) {
        unsigned u = wbuf[wid][e];
        int row = row0 + (int)(u >> 13);
        int code = (int)(u & 8191u);
        unsigned slot = atomicAdd(&cnt[row], 1u);
        if (slot < CANDCAP) cand[(size_t)row * CANDCAP + slot] = (unsigned short)code;
    }
#undef LOADR
#undef MFMAS
#undef EPI
}

// ---------------- exact resolve (verbatim from passing rounds 6-7) ----------
__global__ __launch_bounds__(256) void vq_exact_kernel(
    const float* __restrict__ z, const float* __restrict__ cb,
    const float* __restrict__ zsq, const float* __restrict__ csq,
    const unsigned* __restrict__ cnt, const unsigned short* __restrict__ cand,
    unsigned* __restrict__ ovl, unsigned* __restrict__ ovc,
    float* __restrict__ idxF) {
    __shared__ float zrow[4][DIM];
    const int wid = threadIdx.x >> 6, lane = threadIdx.x & 63;
    const int row = blockIdx.x * 4 + wid;

    float4 zv4 = *reinterpret_cast<const float4*>(&z[(size_t)row * DIM + lane * 4]);
    *reinterpret_cast<float4*>(&zrow[wid][lane * 4]) = zv4;
    __syncthreads();

    const unsigned c = cnt[row];
    if (c == 0 || c > CANDCAP) {
        if (lane == 0) { unsigned s = atomicAdd(ovc, 1u); ovl[s] = row; }
        return;
    }

    const float Zr = zsq[row];
    const float4* cb4 = reinterpret_cast<const float4*>(cb);
    float best = 3.4e38f;
    int   bi   = 0x7FFFFFFF;

    for (int j = lane; j < (int)c; j += 64) {
        int k = cand[(size_t)row * CANDCAP + j];
        float a = 0.0f;
        #pragma unroll 8
        for (int q = 0; q < 64; ++q) {
            float4 cv = cb4[(size_t)k * 64 + q];
            float4 zv = *reinterpret_cast<const float4*>(&zrow[wid][q * 4]);
            a = fmaf(zv.x, cv.x, a); a = fmaf(zv.y, cv.y, a);
            a = fmaf(zv.z, cv.z, a); a = fmaf(zv.w, cv.w, a);
        }
        float sv = __fadd_rn(__fsub_rn(Zr, __fmul_rn(2.0f, a)), csq[k]);
        if (sv < best || (sv == best && k < bi)) { best = sv; bi = k; }
    }
    #pragma unroll
    for (int mk = 32; mk >= 1; mk >>= 1) {
        float ov = __shfl_xor(best, mk);
        int   oi = __shfl_xor(bi, mk);
        if (ov < best || (ov == best && oi < bi)) { best = ov; bi = oi; }
    }
    if (lane == 0) idxF[row] = (float)bi;
}

// Full scan for overflow rows (expected 0). Bitwise chain, first-index ties.
__global__ __launch_bounds__(256) void vq_cleanup_kernel(
    const float* __restrict__ z, const float* __restrict__ cb,
    const float* __restrict__ zsq, const float* __restrict__ csq,
    const unsigned* __restrict__ ovl, const unsigned* __restrict__ ovc,
    float* __restrict__ idxF) {
    __shared__ float zrow[DIM];
    __shared__ float wv[4]; __shared__ int wi[4];
    const int lane = threadIdx.x & 63, wid = threadIdx.x >> 6;
    const unsigned count = *ovc;
    for (unsigned w = blockIdx.x; w < count; w += gridDim.x) {
        const int row = ovl[w];
        __syncthreads();
        *reinterpret_cast<float4*>(&zrow[threadIdx.x * 4 & (DIM - 1)]) =
            *reinterpret_cast<const float4*>(&z[(size_t)row * DIM + (threadIdx.x * 4 & (DIM - 1))]);
        __syncthreads();
        const float Zr = zsq[row];
        const float4* cb4 = reinterpret_cast<const float4*>(cb);
        float best = 3.4e38f; int bi = 0x7FFFFFFF;
        for (int k = threadIdx.x; k < KCB; k += 256) {
            float a = 0.0f;
            #pragma unroll 8
            for (int q = 0; q < 64; ++q) {
                float4 cv = cb4[(size_t)k * 64 + q];
                float4 zv = *reinterpret_cast<const float4*>(&zrow[q * 4]);
                a = fmaf(zv.x, cv.x, a); a = fmaf(zv.y, cv.y, a);
                a = fmaf(zv.z, cv.z, a); a = fmaf(zv.w, cv.w, a);
            }
            float sv = __fadd_rn(__fsub_rn(Zr, __fmul_rn(2.0f, a)), csq[k]);
            if (sv < best || (sv == best && k < bi)) { best = sv; bi = k; }
        }
        #pragma unroll
        for (int mk = 32; mk >= 1; mk >>= 1) {
            float ov = __shfl_xor(best, mk);
            int   oi = __shfl_xor(bi, mk);
            if (ov < best || (ov == best && oi < bi)) { best = ov; bi = oi; }
        }
        if (lane == 0) { wv[wid] = best; wi[wid] = bi; }
        __syncthreads();
        if (threadIdx.x == 0) {
            #pragma unroll
            for (int u = 1; u < 4; ++u)
                if (wv[u] < best || (wv[u] == best && wi[u] < bi)) { best = wv[u]; bi = wi[u]; }
            idxF[row] = (float)bi;
        }
    }
}

__global__ void vq_gather_kernel(const float* __restrict__ cb,
                                 const float* __restrict__ idxF,
                                 float4* __restrict__ out4) {
    int g = blockIdx.x * blockDim.x + threadIdx.x;
    const float4* cb4 = reinterpret_cast<const float4*>(cb);
    for (int i = g; i < NROWS * 64; i += gridDim.x * blockDim.x) {
        int row = i >> 6, q = i & 63;
        int idx = (int)idxF[row];
        out4[i] = cb4[(size_t)idx * 64 + q];
    }
}

extern "C" void kernel_launch(void* const* d_in, const int* in_sizes, int n_in,
                              void* d_out, int out_size, void* d_ws, size_t ws_size,
                              hipStream_t stream) {
    const float* z  = (const float*)d_in[0];
    const float* cb = (const float*)d_in[1];
    float* out = (float*)d_out;

    unsigned short* candp = (unsigned short*)(out + OFF_CAND);
    unsigned*       cntp  = (unsigned*)(out + OFF_CNT);
    float*          zsq   = out + OFF_ZSQ;
    float*          csq   = out + OFF_CSQ;
    float*          csq1  = out + OFF_CSQ1;
    unsigned*       ovl   = (unsigned*)(out + OFF_OVL);
    unsigned*       ovc   = (unsigned*)(out + OFF_OVC);
    char*           img   = (char*)(out + OFF_IMG);
    float*          idxF  = out + OFF_IDX;

    vq_sumsq2_kernel<<<(NROWS + KCB) / 256, 256, 0, stream>>>(z, cb, zsq, csq);
    vq_prepB_kernel<<<1057, 256, 0, stream>>>(cb, csq, img, csq1, cntp, ovc);
    vq_screen_kernel<<<NROWS / 128, 512, 0, stream>>>(z, img, csq1, cntp, candp);
    vq_exact_kernel<<<NROWS / 4, 256, 0, stream>>>(z, cb, zsq, csq, cntp, candp, ovl, ovc, idxF);
    vq_cleanup_kernel<<<64, 256, 0, stream>>>(z, cb, zsq, csq, ovl, ovc, idxF);
    vq_gather_kernel<<<2048, 256, 0, stream>>>(cb, idxF, (float4*)out);
}

// Round 9
// 288.160 us; speedup vs baseline: 4.7867x; 1.0375x over previous
//
#include <hip/hip_runtime.h>

// Vector quantization: z [32768,256] f32, codebook [8192,256] f32
// outputs: z_q [32768,256] f32, indices [32768] (as float)
//
// bf16 MFMA screen (margin-bounded candidate superset) + exact resolve with
// the bitwise round-2 f32 chain (absmax 0 in rounds 2-8).
// Screen v4: register-streamed B (round 8), setprio removed (m190: priority
// pinning starves the partner wave's prefetch issue in lockstep-period loops).
// Scratch lives in d_ws when large enough -> exact/cleanup write z_q directly
// (gather pass eliminated); otherwise falls back to the d_out-scratch layout.

#define NROWS 32768
#define DIM   256
#define KCB   8192
#define CANDCAP 128
#define MARGIN  4.5e-4f
#define WBUF    320

// scratch byte offsets (from scratch base SB = d_ws or d_out)
#define SB_CAND  0u          // u16 [32768][128]  8 MB
#define SB_CNT   8388608u    // u32 [32768]
#define SB_ZSQ   8519680u    // f32 [32768]
#define SB_CSQ   8650752u    // f32 [8192]
#define SB_CSQ1  8683520u    // f32 [8192]
#define SB_OVL   8716288u    // u32 [32768]
#define SB_OVC   8847360u    // u32 (+pad)
#define SB_IMG   8847424u    // B tile image [512][8][64]x16B = 4 MB (16B-aligned)
#define SB_NEED  13049920u   // img end + 8 KB over-read slack

using bf16x8 = __attribute__((ext_vector_type(8))) short;
using f32x4  = __attribute__((ext_vector_type(4))) float;

__device__ __forceinline__ unsigned short bf16rne(float f) {
    unsigned u = __float_as_uint(f);
    unsigned r = u + 0x7FFFu + ((u >> 16) & 1u);
    return (unsigned short)(r >> 16);
}

// numpy pairwise sum of squares, n=256, bitwise-faithful (verified rounds 2-8).
__device__ float np_sumsq_256(const float* __restrict__ p) {
#pragma clang fp contract(off)
    float blk[2];
    #pragma unroll
    for (int b = 0; b < 2; ++b) {
        const float* q = p + b * 128;
        float r[8];
        #pragma unroll
        for (int j = 0; j < 8; ++j) r[j] = __fmul_rn(q[j], q[j]);
        for (int i = 8; i < 128; i += 8) {
            #pragma unroll
            for (int j = 0; j < 8; ++j)
                r[j] = __fadd_rn(r[j], __fmul_rn(q[i + j], q[i + j]));
        }
        blk[b] = __fadd_rn(
            __fadd_rn(__fadd_rn(r[0], r[1]), __fadd_rn(r[2], r[3])),
            __fadd_rn(__fadd_rn(r[4], r[5]), __fadd_rn(r[6], r[7])));
    }
    return __fadd_rn(blk[0], blk[1]);
}

// Fused prep: B tile image convert + csq/csq1 + zsq + counter init.
// B image: [T 512][kk 8][s 64] x 16B; s = lhi*16 + code, content = bf16x8 of
// cb[T*16+code][kk*32+lhi*8 .. +8).
__global__ void vq_prep_kernel(const float* __restrict__ z,
                               const float* __restrict__ cb,
                               char* __restrict__ img,
                               float* __restrict__ zsq, float* __restrict__ csq,
                               float* __restrict__ csq1,
                               unsigned* __restrict__ cnt, unsigned* __restrict__ ovc) {
    int t = blockIdx.x * 256 + threadIdx.x;
    if (t < NROWS) cnt[t] = 0;
    if (t == 0) *ovc = 0;
    if (t < 262144) {
        int s = t & 63, kk = (t >> 6) & 7, T = t >> 9;
        int code = s & 15, lhi = s >> 4;
        const float* src = cb + (size_t)(T * 16 + code) * DIM + kk * 32 + lhi * 8;
        float4 v0 = *reinterpret_cast<const float4*>(src);
        float4 v1 = *reinterpret_cast<const float4*>(src + 4);
        uint4 o;
        o.x = (unsigned)bf16rne(v0.x) | ((unsigned)bf16rne(v0.y) << 16);
        o.y = (unsigned)bf16rne(v0.z) | ((unsigned)bf16rne(v0.w) << 16);
        o.z = (unsigned)bf16rne(v1.x) | ((unsigned)bf16rne(v1.y) << 16);
        o.w = (unsigned)bf16rne(v1.z) | ((unsigned)bf16rne(v1.w) << 16);
        *reinterpret_cast<uint4*>(img + (size_t)T * 8192 + kk * 1024 + s * 16) = o;
    } else if (t < 262144 + KCB) {
        int k = t - 262144;
        float s = np_sumsq_256(cb + (size_t)k * DIM);
        csq[k] = s;
        csq1[k] = s + 1.0f;
    } else if (t < 262144 + KCB + NROWS) {
        int r = t - 262144 - KCB;
        zsq[r] = np_sumsq_256(z + (size_t)r * DIM);
    }
}

// ---------------- register-streamed MFMA screen ----------------
// Grid 256 x 512 thr (8 waves = 2 wr x 4 wc). Wave: 64 rows x 2048 codes as
// 128 16-code tiles. B tile = 8 x dwordx4 per lane, double-buffered in NAMED
// registers; no LDS staging, no loop barriers, no setprio.
__global__ __launch_bounds__(512, 2) void vq_screen_kernel(
    const float* __restrict__ z, const char* __restrict__ img,
    const float* __restrict__ csq1,
    unsigned* __restrict__ cnt, unsigned short* __restrict__ cand) {
    __shared__ unsigned runmin[128];
    __shared__ unsigned wcnt[8];
    __shared__ unsigned wbuf[8][WBUF];
    const int tid = threadIdx.x, lane = tid & 63, wid = tid >> 6;
    const int wr = wid >> 2, wc = wid & 3;
    const int l15 = lane & 15, lhi = lane >> 4;
    const int row0 = blockIdx.x * 128;
    const int tbase = wc * 128;

    // A fragments (one-time bf16 convert from raw z)
    bf16x8 ah[4][8];
    #pragma unroll
    for (int m = 0; m < 4; ++m) {
        const float* zr = z + (size_t)(row0 + wr * 64 + m * 16 + l15) * DIM;
        #pragma unroll
        for (int kk = 0; kk < 8; ++kk) {
            float4 v0 = *reinterpret_cast<const float4*>(zr + kk * 32 + lhi * 8);
            float4 v1 = *reinterpret_cast<const float4*>(zr + kk * 32 + lhi * 8 + 4);
            uint4 o;
            o.x = (unsigned)bf16rne(v0.x) | ((unsigned)bf16rne(v0.y) << 16);
            o.y = (unsigned)bf16rne(v0.z) | ((unsigned)bf16rne(v0.w) << 16);
            o.z = (unsigned)bf16rne(v1.x) | ((unsigned)bf16rne(v1.y) << 16);
            o.w = (unsigned)bf16rne(v1.z) | ((unsigned)bf16rne(v1.w) << 16);
            ah[m][kk] = __builtin_bit_cast(bf16x8, o);
        }
    }

    if (tid < 128) runmin[tid] = 0x7F800000u;   // +inf (s'' > 0 -> uint-monotone)
    if (tid < 8) wcnt[tid] = 0;
    __syncthreads();                            // the only block barrier

    f32x4 acc[4];
    #pragma unroll
    for (int m = 0; m < 4; ++m) acc[m] = (f32x4){0.f, 0.f, 0.f, 0.f};

    const char*  gp = img + (size_t)tbase * 8192 + (size_t)lane * 16;
    const float* cp = csq1 + tbase * 16 + l15;
    int codeb = tbase * 16 + l15;

    uint4 bA[8]; float csA;
    uint4 bB[8]; float csB;

    auto PUSH = [&](int lr, int code) {
        unsigned pi = atomicAdd(&wcnt[wid], 1u);
        if (pi < WBUF) wbuf[wid][pi] = ((unsigned)lr << 13) | (unsigned)code;
        else {
            int grow = row0 + lr;
            unsigned gs = atomicAdd(&cnt[grow], 1u);
            if (gs < CANDCAP) cand[(size_t)grow * CANDCAP + gs] = (unsigned short)code;
        }
    };

#define LOADR(bh, cs)                                                     \
    {                                                                     \
        _Pragma("unroll")                                                 \
        for (int kk = 0; kk < 8; ++kk)                                    \
            bh[kk] = *reinterpret_cast<const uint4*>(gp + kk * 1024);     \
        cs = *cp;                                                         \
        gp += 8192; cp += 16;                                             \
    }

#define MFMAS(bh)                                                         \
    {                                                                     \
        _Pragma("unroll")                                                 \
        for (int kk = 0; kk < 8; ++kk) {                                  \
            bf16x8 bhv = __builtin_bit_cast(bf16x8, bh[kk]);              \
            _Pragma("unroll")                                             \
            for (int m = 0; m < 4; ++m)                                   \
                acc[m] = __builtin_amdgcn_mfma_f32_16x16x32_bf16(         \
                    ah[m][kk], bhv, acc[m], 0, 0, 0);                     \
        }                                                                 \
    }

#define EPI(csv)                                                          \
    {                                                                     \
        _Pragma("unroll")                                                 \
        for (int m = 0; m < 4; ++m) {                                     \
            const int lr0 = wr * 64 + m * 16 + lhi * 4;                   \
            uint4 rmb = *reinterpret_cast<const uint4*>(&runmin[lr0]);    \
            float s0 = fmaf(acc[m][0], -2.0f, csv);                       \
            float s1 = fmaf(acc[m][1], -2.0f, csv);                       \
            float s2 = fmaf(acc[m][2], -2.0f, csv);                       \
            float s3 = fmaf(acc[m][3], -2.0f, csv);                       \
            bool c0 = s0 < __uint_as_float(rmb.x) + MARGIN;               \
            bool c1 = s1 < __uint_as_float(rmb.y) + MARGIN;               \
            bool c2 = s2 < __uint_as_float(rmb.z) + MARGIN;               \
            bool c3 = s3 < __uint_as_float(rmb.w) + MARGIN;               \
            if (__any(c0 | c1 | c2 | c3)) {                               \
                if (c0) { if (s0 < __uint_as_float(rmb.x)) atomicMin(&runmin[lr0 + 0], __float_as_uint(s0)); PUSH(lr0 + 0, codeb); } \
                if (c1) { if (s1 < __uint_as_float(rmb.y)) atomicMin(&runmin[lr0 + 1], __float_as_uint(s1)); PUSH(lr0 + 1, codeb); } \
                if (c2) { if (s2 < __uint_as_float(rmb.z)) atomicMin(&runmin[lr0 + 2], __float_as_uint(s2)); PUSH(lr0 + 2, codeb); } \
                if (c3) { if (s3 < __uint_as_float(rmb.w)) atomicMin(&runmin[lr0 + 3], __float_as_uint(s3)); PUSH(lr0 + 3, codeb); } \
            }                                                             \
            acc[m] = (f32x4){0.f, 0.f, 0.f, 0.f};                         \
        }                                                                 \
        codeb += 16;                                                      \
    }

    // prologue: tile 0 with self-bound epilogue (runmin may still be +inf)
    LOADR(bA, csA);                 // tile 0
    LOADR(bB, csB);                 // tile 1
    MFMAS(bA);
    {
        #pragma unroll
        for (int m = 0; m < 4; ++m) {
            const int lr0 = wr * 64 + m * 16 + lhi * 4;
            #pragma unroll
            for (int r = 0; r < 4; ++r) {
                float s2 = fmaf(acc[m][r], -2.0f, csA);
                float sm = s2;
                sm = fminf(sm, __shfl_xor(sm, 1));
                sm = fminf(sm, __shfl_xor(sm, 2));
                sm = fminf(sm, __shfl_xor(sm, 4));
                sm = fminf(sm, __shfl_xor(sm, 8));
                if (l15 == 0) atomicMin(&runmin[lr0 + r], __float_as_uint(sm));
                if (s2 < sm + MARGIN) PUSH(lr0 + r, codeb);
            }
            acc[m] = (f32x4){0.f, 0.f, 0.f, 0.f};
        }
        codeb += 16;
    }
    LOADR(bA, csA);                 // tile 2
    MFMAS(bB);
    EPI(csB);                       // tile 1

    for (int ct = 2; ct < 128; ct += 2) {
        LOADR(bB, csB);             // tile ct+1
        MFMAS(bA);
        EPI(csA);                   // tile ct
        LOADR(bA, csA);             // tile ct+2 (ct=126: over-read, unused)
        MFMAS(bB);
        EPI(csB);                   // tile ct+1
    }

    // flush wave-local candidate buffer to global per-row lists
    unsigned n = wcnt[wid]; if (n > WBUF) n = WBUF;
    for (unsigned e = lane; e < n; e += 64) {
        unsigned u = wbuf[wid][e];
        int row = row0 + (int)(u >> 13);
        int code = (int)(u & 8191u);
        unsigned slot = atomicAdd(&cnt[row], 1u);
        if (slot < CANDCAP) cand[(size_t)row * CANDCAP + slot] = (unsigned short)code;
    }
#undef LOADR
#undef MFMAS
#undef EPI
}

// ---------------- exact resolve (round 6-8 chain) + optional fused gather ---
__global__ __launch_bounds__(256) void vq_exact_kernel(
    const float* __restrict__ z, const float* __restrict__ cb,
    const float* __restrict__ zsq, const float* __restrict__ csq,
    const unsigned* __restrict__ cnt, const unsigned short* __restrict__ cand,
    unsigned* __restrict__ ovl, unsigned* __restrict__ ovc,
    float* __restrict__ idxF, float4* __restrict__ outz, int fused) {
    __shared__ float zrow[4][DIM];
    const int wid = threadIdx.x >> 6, lane = threadIdx.x & 63;
    const int row = blockIdx.x * 4 + wid;

    float4 zv4 = *reinterpret_cast<const float4*>(&z[(size_t)row * DIM + lane * 4]);
    *reinterpret_cast<float4*>(&zrow[wid][lane * 4]) = zv4;
    __syncthreads();

    const unsigned c = cnt[row];
    if (c == 0 || c > CANDCAP) {
        if (lane == 0) { unsigned s = atomicAdd(ovc, 1u); ovl[s] = row; }
        return;
    }

    const float Zr = zsq[row];
    const float4* cb4 = reinterpret_cast<const float4*>(cb);
    float best = 3.4e38f;
    int   bi   = 0x7FFFFFFF;

    for (int j = lane; j < (int)c; j += 64) {
        int k = cand[(size_t)row * CANDCAP + j];
        float a = 0.0f;
        #pragma unroll 8
        for (int q = 0; q < 64; ++q) {
            float4 cv = cb4[(size_t)k * 64 + q];
            float4 zv = *reinterpret_cast<const float4*>(&zrow[wid][q * 4]);
            a = fmaf(zv.x, cv.x, a); a = fmaf(zv.y, cv.y, a);
            a = fmaf(zv.z, cv.z, a); a = fmaf(zv.w, cv.w, a);
        }
        float sv = __fadd_rn(__fsub_rn(Zr, __fmul_rn(2.0f, a)), csq[k]);
        if (sv < best || (sv == best && k < bi)) { best = sv; bi = k; }
    }
    #pragma unroll
    for (int mk = 32; mk >= 1; mk >>= 1) {
        float ov = __shfl_xor(best, mk);
        int   oi = __shfl_xor(bi, mk);
        if (ov < best || (ov == best && oi < bi)) { best = ov; bi = oi; }
    }
    if (lane == 0) idxF[row] = (float)bi;
    if (fused) outz[(size_t)row * 64 + lane] = cb4[(size_t)bi * 64 + lane];
}

// Full scan for overflow rows (expected 0). Bitwise chain, first-index ties.
__global__ __launch_bounds__(256) void vq_cleanup_kernel(
    const float* __restrict__ z, const float* __restrict__ cb,
    const float* __restrict__ zsq, const float* __restrict__ csq,
    const unsigned* __restrict__ ovl, const unsigned* __restrict__ ovc,
    float* __restrict__ idxF, float4* __restrict__ outz, int fused) {
    __shared__ float zrow[DIM];
    __shared__ float wv[4]; __shared__ int wi[4];
    __shared__ int sbi;
    const int lane = threadIdx.x & 63, wid = threadIdx.x >> 6;
    const unsigned count = *ovc;
    for (unsigned w = blockIdx.x; w < count; w += gridDim.x) {
        const int row = ovl[w];
        __syncthreads();
        *reinterpret_cast<float4*>(&zrow[threadIdx.x * 4 & (DIM - 1)]) =
            *reinterpret_cast<const float4*>(&z[(size_t)row * DIM + (threadIdx.x * 4 & (DIM - 1))]);
        __syncthreads();
        const float Zr = zsq[row];
        const float4* cb4 = reinterpret_cast<const float4*>(cb);
        float best = 3.4e38f; int bi = 0x7FFFFFFF;
        for (int k = threadIdx.x; k < KCB; k += 256) {
            float a = 0.0f;
            #pragma unroll 8
            for (int q = 0; q < 64; ++q) {
                float4 cv = cb4[(size_t)k * 64 + q];
                float4 zv = *reinterpret_cast<const float4*>(&zrow[q * 4]);
                a = fmaf(zv.x, cv.x, a); a = fmaf(zv.y, cv.y, a);
                a = fmaf(zv.z, cv.z, a); a = fmaf(zv.w, cv.w, a);
            }
            float sv = __fadd_rn(__fsub_rn(Zr, __fmul_rn(2.0f, a)), csq[k]);
            if (sv < best || (sv == best && k < bi)) { best = sv; bi = k; }
        }
        #pragma unroll
        for (int mk = 32; mk >= 1; mk >>= 1) {
            float ov = __shfl_xor(best, mk);
            int   oi = __shfl_xor(bi, mk);
            if (ov < best || (ov == best && oi < bi)) { best = ov; bi = oi; }
        }
        if (lane == 0) { wv[wid] = best; wi[wid] = bi; }
        __syncthreads();
        if (threadIdx.x == 0) {
            #pragma unroll
            for (int u = 1; u < 4; ++u)
                if (wv[u] < best || (wv[u] == best && wi[u] < bi)) { best = wv[u]; bi = wi[u]; }
            idxF[row] = (float)best >= 0 ? (float)bi : (float)bi;  // write idx
            sbi = bi;
        }
        __syncthreads();
        if (fused && threadIdx.x < 64)
            outz[(size_t)row * 64 + threadIdx.x] = cb4[(size_t)sbi * 64 + threadIdx.x];
    }
}

__global__ void vq_gather_kernel(const float* __restrict__ cb,
                                 const float* __restrict__ idxF,
                                 float4* __restrict__ out4) {
    int g = blockIdx.x * blockDim.x + threadIdx.x;
    const float4* cb4 = reinterpret_cast<const float4*>(cb);
    for (int i = g; i < NROWS * 64; i += gridDim.x * blockDim.x) {
        int row = i >> 6, q = i & 63;
        int idx = (int)idxF[row];
        out4[i] = cb4[(size_t)idx * 64 + q];
    }
}

extern "C" void kernel_launch(void* const* d_in, const int* in_sizes, int n_in,
                              void* d_out, int out_size, void* d_ws, size_t ws_size,
                              hipStream_t stream) {
    const float* z  = (const float*)d_in[0];
    const float* cb = (const float*)d_in[1];
    float* out = (float*)d_out;

    const int fused = (ws_size >= (size_t)SB_NEED) ? 1 : 0;
    char* SB = fused ? (char*)d_ws : (char*)d_out;

    unsigned short* candp = (unsigned short*)(SB + SB_CAND);
    unsigned*       cntp  = (unsigned*)(SB + SB_CNT);
    float*          zsq   = (float*)(SB + SB_ZSQ);
    float*          csq   = (float*)(SB + SB_CSQ);
    float*          csq1  = (float*)(SB + SB_CSQ1);
    unsigned*       ovl   = (unsigned*)(SB + SB_OVL);
    unsigned*       ovc   = (unsigned*)(SB + SB_OVC);
    char*           img   = SB + SB_IMG;
    float*          idxF  = out + 8388608;   // output 1 (indices as float)

    vq_prep_kernel<<<(262144 + KCB + NROWS + 255) / 256, 256, 0, stream>>>(
        z, cb, img, zsq, csq, csq1, cntp, ovc);
    vq_screen_kernel<<<NROWS / 128, 512, 0, stream>>>(z, img, csq1, cntp, candp);
    vq_exact_kernel<<<NROWS / 4, 256, 0, stream>>>(
        z, cb, zsq, csq, cntp, candp, ovl, ovc, idxF, (float4*)out, fused);
    vq_cleanup_kernel<<<64, 256, 0, stream>>>(
        z, cb, zsq, csq, ovl, ovc, idxF, (float4*)out, fused);
    if (!fused)
        vq_gather_kernel<<<2048, 256, 0, stream>>>(cb, idxF, (float4*)out);
}

// Round 10
// 286.631 us; speedup vs baseline: 4.8122x; 1.0053x over previous
//
#include <hip/hip_runtime.h>

// Vector quantization: z [32768,256] f32, codebook [8192,256] f32
// outputs: z_q [32768,256] f32, indices [32768] (as float)
//
// bf16 MFMA screen (margin-bounded candidate superset) + exact resolve with
// the bitwise round-2 f32 chain (absmax 0 in rounds 2-9).
// Screen v5: register-streamed B, tile split into 4 {2-load + 8-MFMA} chunks
// so prefetch issue interleaves inside the MFMA stream (phase fragmentation;
// round-9 model: monolithic wait->burst->EPI phases lock the SIMD's 2 waves).

#define NROWS 32768
#define DIM   256
#define KCB   8192
#define CANDCAP 128
#define MARGIN  4.5e-4f
#define WBUF    320

// scratch byte offsets (from scratch base SB = d_ws or d_out)
#define SB_CAND  0u          // u16 [32768][128]  8 MB
#define SB_CNT   8388608u    // u32 [32768]
#define SB_ZSQ   8519680u    // f32 [32768]
#define SB_CSQ   8650752u    // f32 [8192]
#define SB_CSQ1  8683520u    // f32 [8192]
#define SB_OVL   8716288u    // u32 [32768]
#define SB_OVC   8847360u    // u32 (+pad)
#define SB_IMG   8847424u    // B tile image [512][8][64]x16B = 4 MB (16B-aligned)
#define SB_NEED  13041728u   // img end

using bf16x8 = __attribute__((ext_vector_type(8))) short;
using f32x4  = __attribute__((ext_vector_type(4))) float;

__device__ __forceinline__ unsigned short bf16rne(float f) {
    unsigned u = __float_as_uint(f);
    unsigned r = u + 0x7FFFu + ((u >> 16) & 1u);
    return (unsigned short)(r >> 16);
}

// numpy pairwise sum of squares, n=256, bitwise-faithful (rounds 2-9), with
// float4 loads (same multiply/add ORDER -> bit-identical result).
__device__ float np_sumsq_256(const float* __restrict__ p) {
#pragma clang fp contract(off)
    float blk[2];
    #pragma unroll
    for (int b = 0; b < 2; ++b) {
        const float4* q4 = reinterpret_cast<const float4*>(p + b * 128);
        float4 a0 = q4[0], a1 = q4[1];
        float r[8];
        r[0] = __fmul_rn(a0.x, a0.x); r[1] = __fmul_rn(a0.y, a0.y);
        r[2] = __fmul_rn(a0.z, a0.z); r[3] = __fmul_rn(a0.w, a0.w);
        r[4] = __fmul_rn(a1.x, a1.x); r[5] = __fmul_rn(a1.y, a1.y);
        r[6] = __fmul_rn(a1.z, a1.z); r[7] = __fmul_rn(a1.w, a1.w);
        #pragma unroll
        for (int i = 2; i < 32; i += 2) {
            a0 = q4[i]; a1 = q4[i + 1];
            r[0] = __fadd_rn(r[0], __fmul_rn(a0.x, a0.x));
            r[1] = __fadd_rn(r[1], __fmul_rn(a0.y, a0.y));
            r[2] = __fadd_rn(r[2], __fmul_rn(a0.z, a0.z));
            r[3] = __fadd_rn(r[3], __fmul_rn(a0.w, a0.w));
            r[4] = __fadd_rn(r[4], __fmul_rn(a1.x, a1.x));
            r[5] = __fadd_rn(r[5], __fmul_rn(a1.y, a1.y));
            r[6] = __fadd_rn(r[6], __fmul_rn(a1.z, a1.z));
            r[7] = __fadd_rn(r[7], __fmul_rn(a1.w, a1.w));
        }
        blk[b] = __fadd_rn(
            __fadd_rn(__fadd_rn(r[0], r[1]), __fadd_rn(r[2], r[3])),
            __fadd_rn(__fadd_rn(r[4], r[5]), __fadd_rn(r[6], r[7])));
    }
    return __fadd_rn(blk[0], blk[1]);
}

// Fused prep: B tile image convert + csq/csq1 + zsq + counter init.
// B image: [T 512][kk 8][s 64] x 16B; s = lhi*16 + code, content = bf16x8 of
// cb[T*16+code][kk*32+lhi*8 .. +8).
__global__ void vq_prep_kernel(const float* __restrict__ z,
                               const float* __restrict__ cb,
                               char* __restrict__ img,
                               float* __restrict__ zsq, float* __restrict__ csq,
                               float* __restrict__ csq1,
                               unsigned* __restrict__ cnt, unsigned* __restrict__ ovc) {
    int t = blockIdx.x * 256 + threadIdx.x;
    if (t < NROWS) cnt[t] = 0;
    if (t == 0) *ovc = 0;
    if (t < 262144) {
        int s = t & 63, kk = (t >> 6) & 7, T = t >> 9;
        int code = s & 15, lhi = s >> 4;
        const float* src = cb + (size_t)(T * 16 + code) * DIM + kk * 32 + lhi * 8;
        float4 v0 = *reinterpret_cast<const float4*>(src);
        float4 v1 = *reinterpret_cast<const float4*>(src + 4);
        uint4 o;
        o.x = (unsigned)bf16rne(v0.x) | ((unsigned)bf16rne(v0.y) << 16);
        o.y = (unsigned)bf16rne(v0.z) | ((unsigned)bf16rne(v0.w) << 16);
        o.z = (unsigned)bf16rne(v1.x) | ((unsigned)bf16rne(v1.y) << 16);
        o.w = (unsigned)bf16rne(v1.z) | ((unsigned)bf16rne(v1.w) << 16);
        *reinterpret_cast<uint4*>(img + (size_t)T * 8192 + kk * 1024 + s * 16) = o;
    } else if (t < 262144 + KCB) {
        int k = t - 262144;
        float s = np_sumsq_256(cb + (size_t)k * DIM);
        csq[k] = s;
        csq1[k] = s + 1.0f;
    } else if (t < 262144 + KCB + NROWS) {
        int r = t - 262144 - KCB;
        zsq[r] = np_sumsq_256(z + (size_t)r * DIM);
    }
}

// ---------------- register-streamed, chunk-interleaved MFMA screen ----------
// Grid 256 x 512 thr (8 waves = 2 wr x 4 wc). Wave: 64 rows x 2048 codes as
// 128 16-code tiles. B tile = 8 x dwordx4 per lane, double-buffered in NAMED
// registers; per tile, 4 chunks of {2 next-tile loads + 8 MFMA}.
__global__ __launch_bounds__(512, 2) void vq_screen_kernel(
    const float* __restrict__ z, const char* __restrict__ img,
    const float* __restrict__ csq1,
    unsigned* __restrict__ cnt, unsigned short* __restrict__ cand) {
    __shared__ unsigned runmin[128];
    __shared__ unsigned wcnt[8];
    __shared__ unsigned wbuf[8][WBUF];
    const int tid = threadIdx.x, lane = tid & 63, wid = tid >> 6;
    const int wr = wid >> 2, wc = wid & 3;
    const int l15 = lane & 15, lhi = lane >> 4;
    const int row0 = blockIdx.x * 128;
    const int tbase = wc * 128;

    // A fragments (one-time bf16 convert from raw z)
    bf16x8 ah[4][8];
    #pragma unroll
    for (int m = 0; m < 4; ++m) {
        const float* zr = z + (size_t)(row0 + wr * 64 + m * 16 + l15) * DIM;
        #pragma unroll
        for (int kk = 0; kk < 8; ++kk) {
            float4 v0 = *reinterpret_cast<const float4*>(zr + kk * 32 + lhi * 8);
            float4 v1 = *reinterpret_cast<const float4*>(zr + kk * 32 + lhi * 8 + 4);
            uint4 o;
            o.x = (unsigned)bf16rne(v0.x) | ((unsigned)bf16rne(v0.y) << 16);
            o.y = (unsigned)bf16rne(v0.z) | ((unsigned)bf16rne(v0.w) << 16);
            o.z = (unsigned)bf16rne(v1.x) | ((unsigned)bf16rne(v1.y) << 16);
            o.w = (unsigned)bf16rne(v1.z) | ((unsigned)bf16rne(v1.w) << 16);
            ah[m][kk] = __builtin_bit_cast(bf16x8, o);
        }
    }

    if (tid < 128) runmin[tid] = 0x7F800000u;   // +inf (s'' > 0 -> uint-monotone)
    if (tid < 8) wcnt[tid] = 0;
    __syncthreads();                            // the only block barrier

    f32x4 acc[4];
    #pragma unroll
    for (int m = 0; m < 4; ++m) acc[m] = (f32x4){0.f, 0.f, 0.f, 0.f};

    const char*  gp = img + (size_t)tbase * 8192 + (size_t)lane * 16;
    const float* cp = csq1 + tbase * 16 + l15;
    int codeb = tbase * 16 + l15;

    uint4 bA[8]; float csA;
    uint4 bB[8]; float csB;

    auto PUSH = [&](int lr, int code) {
        unsigned pi = atomicAdd(&wcnt[wid], 1u);
        if (pi < WBUF) wbuf[wid][pi] = ((unsigned)lr << 13) | (unsigned)code;
        else {
            int grow = row0 + lr;
            unsigned gs = atomicAdd(&cnt[grow], 1u);
            if (gs < CANDCAP) cand[(size_t)grow * CANDCAP + gs] = (unsigned short)code;
        }
    };

// 4 chunks: chunk c loads next-tile kk=2c,2c+1 into bnxt then MFMAs current
// kk=2c,2c+1 from bcur. DOLOAD is a literal 0/1.
#define CHUNKS(bcur, bnxt, csn, DOLOAD)                                   \
    {                                                                     \
        _Pragma("unroll")                                                 \
        for (int c = 0; c < 4; ++c) {                                     \
            if (DOLOAD) {                                                 \
                bnxt[2*c]   = *reinterpret_cast<const uint4*>(gp + (2*c) * 1024);     \
                bnxt[2*c+1] = *reinterpret_cast<const uint4*>(gp + (2*c+1) * 1024);   \
                if (c == 0) csn = *cp;                                    \
            }                                                             \
            bf16x8 b0 = __builtin_bit_cast(bf16x8, bcur[2*c]);            \
            bf16x8 b1 = __builtin_bit_cast(bf16x8, bcur[2*c+1]);          \
            _Pragma("unroll")                                             \
            for (int m = 0; m < 4; ++m)                                   \
                acc[m] = __builtin_amdgcn_mfma_f32_16x16x32_bf16(ah[m][2*c], b0, acc[m], 0, 0, 0);   \
            _Pragma("unroll")                                             \
            for (int m = 0; m < 4; ++m)                                   \
                acc[m] = __builtin_amdgcn_mfma_f32_16x16x32_bf16(ah[m][2*c+1], b1, acc[m], 0, 0, 0); \
        }                                                                 \
        if (DOLOAD) { gp += 8192; cp += 16; }                             \
    }

#define EPI(csv)                                                          \
    {                                                                     \
        _Pragma("unroll")                                                 \
        for (int m = 0; m < 4; ++m) {                                     \
            const int lr0 = wr * 64 + m * 16 + lhi * 4;                   \
            uint4 rmb = *reinterpret_cast<const uint4*>(&runmin[lr0]);    \
            float s0 = fmaf(acc[m][0], -2.0f, csv);                       \
            float s1 = fmaf(acc[m][1], -2.0f, csv);                       \
            float s2 = fmaf(acc[m][2], -2.0f, csv);                       \
            float s3 = fmaf(acc[m][3], -2.0f, csv);                       \
            bool c0 = s0 < __uint_as_float(rmb.x) + MARGIN;               \
            bool c1 = s1 < __uint_as_float(rmb.y) + MARGIN;               \
            bool c2 = s2 < __uint_as_float(rmb.z) + MARGIN;               \
            bool c3 = s3 < __uint_as_float(rmb.w) + MARGIN;               \
            if (__any(c0 | c1 | c2 | c3)) {                               \
                if (c0) { if (s0 < __uint_as_float(rmb.x)) atomicMin(&runmin[lr0 + 0], __float_as_uint(s0)); PUSH(lr0 + 0, codeb); } \
                if (c1) { if (s1 < __uint_as_float(rmb.y)) atomicMin(&runmin[lr0 + 1], __float_as_uint(s1)); PUSH(lr0 + 1, codeb); } \
                if (c2) { if (s2 < __uint_as_float(rmb.z)) atomicMin(&runmin[lr0 + 2], __float_as_uint(s2)); PUSH(lr0 + 2, codeb); } \
                if (c3) { if (s3 < __uint_as_float(rmb.w)) atomicMin(&runmin[lr0 + 3], __float_as_uint(s3)); PUSH(lr0 + 3, codeb); } \
            }                                                             \
            acc[m] = (f32x4){0.f, 0.f, 0.f, 0.f};                         \
        }                                                                 \
        codeb += 16;                                                      \
    }

    // prologue: full load of tile 0
    #pragma unroll
    for (int kk = 0; kk < 8; ++kk)
        bA[kk] = *reinterpret_cast<const uint4*>(gp + kk * 1024);
    csA = *cp; gp += 8192; cp += 16;

    // tile 0: self-bound epilogue (runmin may still be +inf)
    CHUNKS(bA, bB, csB, 1);
    {
        #pragma unroll
        for (int m = 0; m < 4; ++m) {
            const int lr0 = wr * 64 + m * 16 + lhi * 4;
            #pragma unroll
            for (int r = 0; r < 4; ++r) {
                float s2 = fmaf(acc[m][r], -2.0f, csA);
                float sm = s2;
                sm = fminf(sm, __shfl_xor(sm, 1));
                sm = fminf(sm, __shfl_xor(sm, 2));
                sm = fminf(sm, __shfl_xor(sm, 4));
                sm = fminf(sm, __shfl_xor(sm, 8));
                if (l15 == 0) atomicMin(&runmin[lr0 + r], __float_as_uint(sm));
                if (s2 < sm + MARGIN) PUSH(lr0 + r, codeb);
            }
            acc[m] = (f32x4){0.f, 0.f, 0.f, 0.f};
        }
        codeb += 16;
    }
    CHUNKS(bB, bA, csA, 1);  EPI(csB);   // tile 1, load tile 2

    for (int t = 2; t < 126; t += 2) {
        CHUNKS(bA, bB, csB, 1);  EPI(csA);   // tile t,   load t+1
        CHUNKS(bB, bA, csA, 1);  EPI(csB);   // tile t+1, load t+2
    }
    CHUNKS(bA, bB, csB, 1);  EPI(csA);       // tile 126, load 127
    CHUNKS(bB, bA, csA, 0);  EPI(csB);       // tile 127, no loads

    // flush wave-local candidate buffer to global per-row lists
    unsigned n = wcnt[wid]; if (n > WBUF) n = WBUF;
    for (unsigned e = lane; e < n; e += 64) {
        unsigned u = wbuf[wid][e];
        int row = row0 + (int)(u >> 13);
        int code = (int)(u & 8191u);
        unsigned slot = atomicAdd(&cnt[row], 1u);
        if (slot < CANDCAP) cand[(size_t)row * CANDCAP + slot] = (unsigned short)code;
    }
#undef CHUNKS
#undef EPI
}

// ---------------- exact resolve (round 6-9 chain) + fused gather ------------
__global__ __launch_bounds__(256) void vq_exact_kernel(
    const float* __restrict__ z, const float* __restrict__ cb,
    const float* __restrict__ zsq, const float* __restrict__ csq,
    const unsigned* __restrict__ cnt, const unsigned short* __restrict__ cand,
    unsigned* __restrict__ ovl, unsigned* __restrict__ ovc,
    float* __restrict__ idxF, float4* __restrict__ outz, int fused) {
    __shared__ float zrow[4][DIM];
    const int wid = threadIdx.x >> 6, lane = threadIdx.x & 63;
    const int row = blockIdx.x * 4 + wid;

    float4 zv4 = *reinterpret_cast<const float4*>(&z[(size_t)row * DIM + lane * 4]);
    *reinterpret_cast<float4*>(&zrow[wid][lane * 4]) = zv4;
    __syncthreads();

    const unsigned c = cnt[row];
    if (c == 0 || c > CANDCAP) {
        if (lane == 0) { unsigned s = atomicAdd(ovc, 1u); ovl[s] = row; }
        return;
    }

    const float Zr = zsq[row];
    const float4* cb4 = reinterpret_cast<const float4*>(cb);
    float best = 3.4e38f;
    int   bi   = 0x7FFFFFFF;

    for (int j = lane; j < (int)c; j += 64) {
        int k = cand[(size_t)row * CANDCAP + j];
        float a = 0.0f;
        #pragma unroll 8
        for (int q = 0; q < 64; ++q) {
            float4 cv = cb4[(size_t)k * 64 + q];
            float4 zv = *reinterpret_cast<const float4*>(&zrow[wid][q * 4]);
            a = fmaf(zv.x, cv.x, a); a = fmaf(zv.y, cv.y, a);
            a = fmaf(zv.z, cv.z, a); a = fmaf(zv.w, cv.w, a);
        }
        float sv = __fadd_rn(__fsub_rn(Zr, __fmul_rn(2.0f, a)), csq[k]);
        if (sv < best || (sv == best && k < bi)) { best = sv; bi = k; }
    }
    #pragma unroll
    for (int mk = 32; mk >= 1; mk >>= 1) {
        float ov = __shfl_xor(best, mk);
        int   oi = __shfl_xor(bi, mk);
        if (ov < best || (ov == best && oi < bi)) { best = ov; bi = oi; }
    }
    if (lane == 0) idxF[row] = (float)bi;
    if (fused) outz[(size_t)row * 64 + lane] = cb4[(size_t)bi * 64 + lane];
}

// Full scan for overflow rows (expected 0). Bitwise chain, first-index ties.
__global__ __launch_bounds__(256) void vq_cleanup_kernel(
    const float* __restrict__ z, const float* __restrict__ cb,
    const float* __restrict__ zsq, const float* __restrict__ csq,
    const unsigned* __restrict__ ovl, const unsigned* __restrict__ ovc,
    float* __restrict__ idxF, float4* __restrict__ outz, int fused) {
    __shared__ float zrow[DIM];
    __shared__ float wv[4]; __shared__ int wi[4];
    __shared__ int sbi;
    const int lane = threadIdx.x & 63, wid = threadIdx.x >> 6;
    const unsigned count = *ovc;
    for (unsigned w = blockIdx.x; w < count; w += gridDim.x) {
        const int row = ovl[w];
        __syncthreads();
        *reinterpret_cast<float4*>(&zrow[threadIdx.x * 4 & (DIM - 1)]) =
            *reinterpret_cast<const float4*>(&z[(size_t)row * DIM + (threadIdx.x * 4 & (DIM - 1))]);
        __syncthreads();
        const float Zr = zsq[row];
        const float4* cb4 = reinterpret_cast<const float4*>(cb);
        float best = 3.4e38f; int bi = 0x7FFFFFFF;
        for (int k = threadIdx.x; k < KCB; k += 256) {
            float a = 0.0f;
            #pragma unroll 8
            for (int q = 0; q < 64; ++q) {
                float4 cv = cb4[(size_t)k * 64 + q];
                float4 zv = *reinterpret_cast<const float4*>(&zrow[q * 4]);
                a = fmaf(zv.x, cv.x, a); a = fmaf(zv.y, cv.y, a);
                a = fmaf(zv.z, cv.z, a); a = fmaf(zv.w, cv.w, a);
            }
            float sv = __fadd_rn(__fsub_rn(Zr, __fmul_rn(2.0f, a)), csq[k]);
            if (sv < best || (sv == best && k < bi)) { best = sv; bi = k; }
        }
        #pragma unroll
        for (int mk = 32; mk >= 1; mk >>= 1) {
            float ov = __shfl_xor(best, mk);
            int   oi = __shfl_xor(bi, mk);
            if (ov < best || (ov == best && oi < bi)) { best = ov; bi = oi; }
        }
        if (lane == 0) { wv[wid] = best; wi[wid] = bi; }
        __syncthreads();
        if (threadIdx.x == 0) {
            #pragma unroll
            for (int u = 1; u < 4; ++u)
                if (wv[u] < best || (wv[u] == best && wi[u] < bi)) { best = wv[u]; bi = wi[u]; }
            idxF[row] = (float)bi;
            sbi = bi;
        }
        __syncthreads();
        if (fused && threadIdx.x < 64)
            outz[(size_t)row * 64 + threadIdx.x] = cb4[(size_t)sbi * 64 + threadIdx.x];
    }
}

__global__ void vq_gather_kernel(const float* __restrict__ cb,
                                 const float* __restrict__ idxF,
                                 float4* __restrict__ out4) {
    int g = blockIdx.x * blockDim.x + threadIdx.x;
    const float4* cb4 = reinterpret_cast<const float4*>(cb);
    for (int i = g; i < NROWS * 64; i += gridDim.x * blockDim.x) {
        int row = i >> 6, q = i & 63;
        int idx = (int)idxF[row];
        out4[i] = cb4[(size_t)idx * 64 + q];
    }
}

extern "C" void kernel_launch(void* const* d_in, const int* in_sizes, int n_in,
                              void* d_out, int out_size, void* d_ws, size_t ws_size,
                              hipStream_t stream) {
    const float* z  = (const float*)d_in[0];
    const float* cb = (const float*)d_in[1];
    float* out = (float*)d_out;

    const int fused = (ws_size >= (size_t)SB_NEED) ? 1 : 0;
    char* SB = fused ? (char*)d_ws : (char*)d_out;

    unsigned short* candp = (unsigned short*)(SB + SB_CAND);
    unsigned*       cntp  = (unsigned*)(SB + SB_CNT);
    float*          zsq   = (float*)(SB + SB_ZSQ);
    float*          csq   = (float*)(SB + SB_CSQ);
    float*          csq1  = (float*)(SB + SB_CSQ1);
    unsigned*       ovl   = (unsigned*)(SB + SB_OVL);
    unsigned*       ovc   = (unsigned*)(SB + SB_OVC);
    char*           img   = SB + SB_IMG;
    float*          idxF  = out + 8388608;   // output 1 (indices as float)

    vq_prep_kernel<<<(262144 + KCB + NROWS + 255) / 256, 256, 0, stream>>>(
        z, cb, img, zsq, csq, csq1, cntp, ovc);
    vq_screen_kernel<<<NROWS / 128, 512, 0, stream>>>(z, img, csq1, cntp, candp);
    vq_exact_kernel<<<NROWS / 4, 256, 0, stream>>>(
        z, cb, zsq, csq, cntp, candp, ovl, ovc, idxF, (float4*)out, fused);
    vq_cleanup_kernel<<<64, 256, 0, stream>>>(
        z, cb, zsq, csq, ovl, ovc, idxF, (float4*)out, fused);
    if (!fused)
        vq_gather_kernel<<<2048, 256, 0, stream>>>(cb, idxF, (float4*)out);
}